// Round 8
// baseline (294.905 us; speedup 1.0000x reference)
//
#include <hip/hip_runtime.h>
#include <hip/hip_fp16.h>

#define N_NODES 100000
#define PAD_N   100096                   // 782 * 128, padded M for GEMM tiles
#define IN_DIM 128
#define HID 128
#define N_REL 2
#define N_EDGES 500000
#define M_SEG (N_REL * N_NODES)          // 200000 (rel,node) segments
#define SCAN_BLK 1024
#define SCAN_NB ((M_SEG + SCAN_BLK - 1) / SCAN_BLK)   // 196

#define CVT_BLOCKS 12500                 // N_NODES*IN_DIM/4 / 256
#define PACK_BLOCKS 48                   // 2*12*8*64 / 256
#define HIST_BLOCKS 1954                 // ceil(N_EDGES/256)

typedef __attribute__((ext_vector_type(8))) _Float16 half8;
typedef __attribute__((ext_vector_type(4))) float float4v;

__device__ __forceinline__ unsigned short f2h(float f) {
    return __half_as_ushort(__float2half(f));   // RNE
}

// ---------------------------------------------------------------------------
// Fused prep: cvt (x fp32->fp16) | pack (weights->B-frag order, fp16) | hist.
// ---------------------------------------------------------------------------
__global__ __launch_bounds__(256) void prep_kernel(
    const float* __restrict__ X, unsigned short* __restrict__ Xb,
    const float* __restrict__ Wroot1, const float* __restrict__ Wrel1,
    const float* __restrict__ Wroot2, const float* __restrict__ Wrel2,
    unsigned short* __restrict__ Wp,
    const int* __restrict__ ei, const int* __restrict__ et,
    unsigned* __restrict__ cnt)
{
    int bid = blockIdx.x;
    if (bid < CVT_BLOCKS) {
        int i = bid * 256 + threadIdx.x;
        if (i >= N_NODES * IN_DIM / 4) return;
        float4 v = ((const float4*)X)[i];
        ushort4 o;
        o.x = f2h(v.x); o.y = f2h(v.y); o.z = f2h(v.z); o.w = f2h(v.w);
        ((ushort4*)Xb)[i] = o;
    } else if (bid < CVT_BLOCKS + PACK_BLOCKS) {
        int tid = (bid - CVT_BLOCKS) * 256 + threadIdx.x;
        int layer = tid / 6144;
        int rem   = tid % 6144;
        int ks    = rem / 512;
        int rem2  = rem % 512;
        int nt    = rem2 / 64;
        int lane  = rem2 % 64;
        int seg = ks >> 2;
        int kl  = (ks & 3) * 32 + (lane >> 4) * 8;
        int chan = nt * 16 + (lane & 15);
        const float* Wroot = layer ? Wroot2 : Wroot1;
        const float* Wrel  = layer ? Wrel2  : Wrel1;
        const float* W = (seg == 0) ? Wroot : (Wrel + (size_t)(seg - 1) * 128 * 128);
        unsigned short* dst = Wp + (size_t)tid * 8;
        #pragma unroll
        for (int j = 0; j < 8; ++j)
            dst[j] = f2h(W[(size_t)(kl + j) * 128 + chan]);
    } else {
        int e = (bid - CVT_BLOCKS - PACK_BLOCKS) * 256 + threadIdx.x;
        if (e >= N_EDGES) return;
        int dst = ei[N_EDGES + e];
        int r = et[e];
        atomicAdd(cnt + (size_t)r * N_NODES + dst, 1u);
    }
}

// ---------------------------------------------------------------------------
// Scan chain for CSR row starts (scan1 -> scan3; scan2 folded into scan3)
// ---------------------------------------------------------------------------
__global__ __launch_bounds__(256) void scan1_kernel(
    const unsigned* __restrict__ cnt,
    unsigned* __restrict__ rs, unsigned* __restrict__ bsums)
{
    __shared__ unsigned sdata[256];
    int t = threadIdx.x;
    int base = blockIdx.x * SCAN_BLK + t * 4;
    unsigned v[4]; unsigned s = 0;
    #pragma unroll
    for (int j = 0; j < 4; ++j) {
        v[j] = (base + j < M_SEG) ? cnt[base + j] : 0u;
        s += v[j];
    }
    sdata[t] = s;
    __syncthreads();
    #pragma unroll
    for (int off = 1; off < 256; off <<= 1) {
        unsigned x = (t >= off) ? sdata[t - off] : 0u;
        __syncthreads();
        if (t >= off) sdata[t] += x;
        __syncthreads();
    }
    unsigned excl = (t > 0) ? sdata[t - 1] : 0u;
    if (t == 255) bsums[blockIdx.x] = sdata[255];
    unsigned run = excl;
    #pragma unroll
    for (int j = 0; j < 4; ++j) {
        if (base + j < M_SEG) rs[base + j] = run;
        run += v[j];
    }
}

// scan3: each block redundantly scans the 196 block sums in LDS (trivial),
// then applies the offset.  Removes the serial single-block scan2 dispatch.
__global__ __launch_bounds__(256) void scan3_kernel(
    unsigned* __restrict__ rs, const unsigned* __restrict__ bsums,
    unsigned* __restrict__ cursor)
{
    __shared__ unsigned sdata[256];
    int t = threadIdx.x;
    sdata[t] = (t < SCAN_NB) ? bsums[t] : 0u;
    __syncthreads();
    #pragma unroll
    for (int off = 1; off < 256; off <<= 1) {
        unsigned x = (t >= off) ? sdata[t - off] : 0u;
        __syncthreads();
        if (t >= off) sdata[t] += x;
        __syncthreads();
    }
    int i = blockIdx.x * blockDim.x + t;
    if (i < M_SEG) {
        int b = i >> 10;
        unsigned add = (b > 0) ? sdata[b - 1] : 0u;
        unsigned v = rs[i] + add;
        rs[i] = v;
        cursor[i] = v;
    }
    if (i == 0) rs[M_SEG] = N_EDGES;
}

__global__ __launch_bounds__(256) void fill_kernel(
    const int* __restrict__ ei, const int* __restrict__ et,
    unsigned* __restrict__ cursor, unsigned* __restrict__ csr)
{
    int e = blockIdx.x * blockDim.x + threadIdx.x;
    if (e >= N_EDGES) return;
    int src = ei[e];
    int dst = ei[N_EDGES + e];
    int r = et[e];
    unsigned pos = atomicAdd(cursor + (size_t)r * N_NODES + dst, 1u);
    csr[pos] = (unsigned)src;
}

// ---------------------------------------------------------------------------
// Gather-aggregate (fp16), standalone: 32 lanes per segment = 2 edge-slots x
// 16 ch-groups (uint4 = 8 fp16 channels).  Tiny register state -> high
// occupancy (8+ waves/SIMD) so the random-row latency is overlapped deeply —
// this is the phase-decoupling ablation vs the fused gemm.
// ---------------------------------------------------------------------------
__global__ __launch_bounds__(256) void gather_kernel(
    const unsigned short* __restrict__ Xb,   // [PAD_N][128] fp16
    const unsigned* __restrict__ rs,
    const unsigned* __restrict__ csr,
    unsigned short* __restrict__ agg)        // [2][PAD_N][128] fp16 means
{
    int t = blockIdx.x * blockDim.x + threadIdx.x;
    int seg = t >> 5;                 // 32 lanes per segment
    int lane = t & 31;
    if (seg >= M_SEG) return;
    const int e2  = lane >> 4;        // edge slot 0..1
    const int c16 = lane & 15;        // channel group (8 ch = uint4)

    unsigned start = rs[seg];
    unsigned end   = rs[seg + 1];

    const uint4* __restrict__ X4 = (const uint4*)Xb;   // 16B units

    __half2 acc[4];
    #pragma unroll
    for (int j = 0; j < 4; ++j) acc[j] = __float2half2_rn(0.f);

    for (unsigned p = start + e2; p < end; p += 2) {
        unsigned s = csr[p];
        uint4 v = X4[(s << 4) | (unsigned)c16];        // 32-bit index, SGPR base
        acc[0] = __hadd2(acc[0], *(const __half2*)&v.x);
        acc[1] = __hadd2(acc[1], *(const __half2*)&v.y);
        acc[2] = __hadd2(acc[2], *(const __half2*)&v.z);
        acc[3] = __hadd2(acc[3], *(const __half2*)&v.w);
    }

    // reduce across the 2 edge slots (lane bit 4)
    #pragma unroll
    for (int j = 0; j < 4; ++j) {
        int other = __shfl_xor(*(const int*)&acc[j], 16, 32);
        acc[j] = __hadd2(acc[j], *(const __half2*)&other);
    }

    if (e2 == 0) {
        unsigned c = end - start;
        float scale = 1.0f / (float)(c > 0u ? c : 1u);
        __half2 s2 = __float2half2_rn(scale);
        uint4 o;
        __half2 r0 = __hmul2(acc[0], s2);
        __half2 r1 = __hmul2(acc[1], s2);
        __half2 r2 = __hmul2(acc[2], s2);
        __half2 r3 = __hmul2(acc[3], s2);
        o.x = *(const unsigned*)&r0;
        o.y = *(const unsigned*)&r1;
        o.z = *(const unsigned*)&r2;
        o.w = *(const unsigned*)&r3;
        int r = seg / N_NODES;
        int n = seg % N_NODES;
        ((uint4*)(agg + ((size_t)r * PAD_N + n) * HID))[c16] = o;
    }
}

// ---------------------------------------------------------------------------
// Pure MFMA GEMM (fp16): 16 rows per wave, A-frags (own row + 2 relation
// means) all LINEAR loads; B from L2 with depth-2 register ping-pong.
// No LDS, no barriers, default launch bounds (forced bounds spilled r4/r5).
// ---------------------------------------------------------------------------
template <bool FINAL>
__global__ __launch_bounds__(256) void gemm_kernel(
    const unsigned short* __restrict__ Xin,   // [PAD_N][128] fp16
    const unsigned short* __restrict__ agg,   // [2][PAD_N][128] fp16 means
    const unsigned short* __restrict__ Wp,    // packed [12][8][64][8] fp16
    const float* __restrict__ bias,           // [128] fp32
    unsigned short* __restrict__ Hout,        // [PAD_N][128] fp16 (!FINAL)
    const float* __restrict__ Wc,             // [128][2] fp32 (FINAL)
    const float* __restrict__ bc,             // [2] fp32 (FINAL)
    float* __restrict__ Out)                  // [N][2] fp32 (FINAL)
{
    const int t    = threadIdx.x;
    const int w    = t >> 6;          // wave 0..3
    const int lane = t & 63;
    const int l15  = lane & 15;
    const int quad = lane >> 4;
    const int rowbase = blockIdx.x * 64 + w * 16;   // this wave's 16 nodes
    const int koff = quad * 8;
    const int node = rowbase + l15;

    // ---- A fragments: all linear (own row + 2 relation mean rows) ----
    const unsigned short* aBase  = Xin + (size_t)node * 128 + koff;
    const unsigned short* gBase0 = agg + (size_t)node * 128 + koff;
    const unsigned short* gBase1 = gBase0 + (size_t)PAD_N * 128;

    half8 ag[2][4];                   // [r][ksl] mean fragments, preloaded
    #pragma unroll
    for (int ksl = 0; ksl < 4; ++ksl) {
        ag[0][ksl] = *(const half8*)(gBase0 + ksl * 32);
        ag[1][ksl] = *(const half8*)(gBase1 + ksl * 32);
    }

    auto ldB = [&](int ks, int nt) -> half8 {
        return *(const half8*)(Wp + ((size_t)(ks * 8 + nt) * 64 + lane) * 8);
    };
    auto ldA = [&](int ks) -> half8 {
        return *(const half8*)(aBase + (ks & 3) * 32);
    };

    float4v acc[8];
    #pragma unroll
    for (int nt = 0; nt < 8; ++nt) {
        float bv = bias[nt * 16 + l15];
        acc[nt] = float4v{bv, bv, bv, bv};
    }

    half8 bb[2][8];                   // ping-pong, ks&1 is compile-time
    half8 ax[2];
    #pragma unroll
    for (int nt = 0; nt < 8; ++nt) bb[0][nt] = ldB(0, nt);
    ax[0] = ldA(0);

    #pragma unroll
    for (int ks = 0; ks < 12; ++ks) {
        if (ks + 1 < 12) {
            #pragma unroll
            for (int nt = 0; nt < 8; ++nt)
                bb[(ks + 1) & 1][nt] = ldB(ks + 1, nt);
            if (ks + 1 < 4) ax[(ks + 1) & 1] = ldA(ks + 1);
        }
        half8 A = (ks < 4) ? ax[ks & 1] : ag[(ks >> 2) - 1][ks & 3];
        #pragma unroll
        for (int nt = 0; nt < 8; ++nt)
            acc[nt] = __builtin_amdgcn_mfma_f32_16x16x32_f16(A, bb[ks & 1][nt], acc[nt], 0, 0, 0);
    }

    if (!FINAL) {
        // D layout: row = quad*4 + rr, col = l15 (within each 16x16 tile)
        #pragma unroll
        for (int rr = 0; rr < 4; ++rr) {
            int n2 = rowbase + quad * 4 + rr;
            unsigned short* hp = Hout + (size_t)n2 * 128 + l15;
            #pragma unroll
            for (int nt = 0; nt < 8; ++nt)
                hp[nt * 16] = f2h(fmaxf(acc[nt][rr], 0.f));
        }
    } else {
        float wc0[8], wc1[8];
        #pragma unroll
        for (int nt = 0; nt < 8; ++nt) {
            wc0[nt] = Wc[(nt * 16 + l15) * 2 + 0];
            wc1[nt] = Wc[(nt * 16 + l15) * 2 + 1];
        }
        float b0 = bc[0], b1 = bc[1];
        #pragma unroll
        for (int rr = 0; rr < 4; ++rr) {
            float l0 = 0.f, l1 = 0.f;
            #pragma unroll
            for (int nt = 0; nt < 8; ++nt) {
                float h = fmaxf(acc[nt][rr], 0.f);
                l0 += h * wc0[nt];
                l1 += h * wc1[nt];
            }
            #pragma unroll
            for (int off = 8; off > 0; off >>= 1) {
                l0 += __shfl_down(l0, off, 16);
                l1 += __shfl_down(l1, off, 16);
            }
            int n2 = rowbase + quad * 4 + rr;
            if (l15 == 0 && n2 < N_NODES) {
                Out[(size_t)n2 * 2 + 0] = l0 + b0;
                Out[(size_t)n2 * 2 + 1] = l1 + b1;
            }
        }
    }
}

extern "C" void kernel_launch(void* const* d_in, const int* in_sizes, int n_in,
                              void* d_out, int out_size, void* d_ws, size_t ws_size,
                              hipStream_t stream)
{
    const float* x      = (const float*)d_in[0];
    const int*   ei     = (const int*)d_in[1];
    const int*   et     = (const int*)d_in[2];
    const float* Wrel1  = (const float*)d_in[3];
    const float* Wroot1 = (const float*)d_in[4];
    const float* b1     = (const float*)d_in[5];
    const float* Wrel2  = (const float*)d_in[6];
    const float* Wroot2 = (const float*)d_in[7];
    const float* b2     = (const float*)d_in[8];
    const float* Wc     = (const float*)d_in[9];
    const float* bc     = (const float*)d_in[10];
    float* out = (float*)d_out;

    char* ws = (char*)d_ws;
    size_t off = 0;
    auto alloc = [&](size_t bytes) {
        void* p = ws + off;
        off += (bytes + 255) & ~(size_t)255;
        return p;
    };
    unsigned short* aggb  = (unsigned short*)alloc((size_t)N_REL * PAD_N * HID * 2);
    unsigned short* xb    = (unsigned short*)alloc((size_t)PAD_N * IN_DIM * 2);
    unsigned short* h1b   = (unsigned short*)alloc((size_t)PAD_N * HID * 2);
    unsigned short* Wp    = (unsigned short*)alloc((size_t)2 * 12 * 8 * 64 * 8 * 2);
    unsigned*       rs    = (unsigned*)alloc((size_t)(M_SEG + 1) * 4);
    unsigned*       cursor= (unsigned*)alloc((size_t)M_SEG * 4);
    unsigned*       bsums = (unsigned*)alloc(256 * 4);
    unsigned*       csr   = (unsigned*)alloc((size_t)N_EDGES * 4);

    const int edge_blocks   = (N_EDGES + 255) / 256;
    const int seg_blocks    = (M_SEG + 255) / 256;
    const int gather_blocks = (M_SEG * 32 + 255) / 256;   // 25000
    const int gemm_blocks   = PAD_N / 64;                 // 1564
    const int prep_blocks   = CVT_BLOCKS + PACK_BLOCKS + HIST_BLOCKS;

    // ---- CSR build + conversions (graph identical for both layers) ----
    hipMemsetAsync(cursor, 0, (size_t)M_SEG * 4, stream);
    prep_kernel<<<prep_blocks, 256, 0, stream>>>(
        x, xb, Wroot1, Wrel1, Wroot2, Wrel2, Wp, ei, et, cursor);
    scan1_kernel<<<SCAN_NB, 256, 0, stream>>>(cursor, rs, bsums);
    scan3_kernel<<<seg_blocks, 256, 0, stream>>>(rs, bsums, cursor);
    fill_kernel<<<edge_blocks, 256, 0, stream>>>(ei, et, cursor, csr);

    // ---- layer 1 ----
    gather_kernel<<<gather_blocks, 256, 0, stream>>>(xb, rs, csr, aggb);
    gemm_kernel<false><<<gemm_blocks, 256, 0, stream>>>(
        xb, aggb, Wp, b1, h1b, nullptr, nullptr, nullptr);

    // ---- layer 2 ----
    gather_kernel<<<gather_blocks, 256, 0, stream>>>(h1b, rs, csr, aggb);
    gemm_kernel<true><<<gemm_blocks, 256, 0, stream>>>(
        h1b, aggb, Wp + (size_t)12 * 8 * 64 * 8, b2, nullptr, Wc, bc, out);
}

// Round 9
// 285.259 us; speedup vs baseline: 1.0338x; 1.0338x over previous
//
#include <hip/hip_runtime.h>
#include <hip/hip_fp16.h>

#define N_NODES 100000
#define PAD_N   100096                   // 782 * 128, padded M for GEMM tiles
#define IN_DIM 128
#define HID 128
#define N_REL 2
#define N_EDGES 500000
#define M_SEG (N_REL * N_NODES)          // 200000 (rel,node) segments
#define SCAN_BLK 1024
#define SCAN_NB ((M_SEG + SCAN_BLK - 1) / SCAN_BLK)   // 196

#define CVT_BLOCKS 12500                 // N_NODES*IN_DIM/4 / 256
#define PACK_BLOCKS 48                   // 2*12*8*64 / 256
#define HIST_BLOCKS 1954                 // ceil(N_EDGES/256)

#define GB_EDGES 48                      // gather batch: 48 edge-rows (12 KB/wave)

typedef __attribute__((ext_vector_type(8))) _Float16 half8;
typedef __attribute__((ext_vector_type(4))) float float4v;

__device__ __forceinline__ unsigned short f2h(float f) {
    return __half_as_ushort(__float2half(f));   // RNE
}

// ---------------------------------------------------------------------------
// Fused prep: cvt (x fp32->fp16) | pack (weights->B-frag order, fp16) | hist.
// ---------------------------------------------------------------------------
__global__ __launch_bounds__(256) void prep_kernel(
    const float* __restrict__ X, unsigned short* __restrict__ Xb,
    const float* __restrict__ Wroot1, const float* __restrict__ Wrel1,
    const float* __restrict__ Wroot2, const float* __restrict__ Wrel2,
    unsigned short* __restrict__ Wp,
    const int* __restrict__ ei, const int* __restrict__ et,
    unsigned* __restrict__ cnt)
{
    int bid = blockIdx.x;
    if (bid < CVT_BLOCKS) {
        int i = bid * 256 + threadIdx.x;
        if (i >= N_NODES * IN_DIM / 4) return;
        float4 v = ((const float4*)X)[i];
        ushort4 o;
        o.x = f2h(v.x); o.y = f2h(v.y); o.z = f2h(v.z); o.w = f2h(v.w);
        ((ushort4*)Xb)[i] = o;
    } else if (bid < CVT_BLOCKS + PACK_BLOCKS) {
        int tid = (bid - CVT_BLOCKS) * 256 + threadIdx.x;
        int layer = tid / 6144;
        int rem   = tid % 6144;
        int ks    = rem / 512;
        int rem2  = rem % 512;
        int nt    = rem2 / 64;
        int lane  = rem2 % 64;
        int seg = ks >> 2;
        int kl  = (ks & 3) * 32 + (lane >> 4) * 8;
        int chan = nt * 16 + (lane & 15);
        const float* Wroot = layer ? Wroot2 : Wroot1;
        const float* Wrel  = layer ? Wrel2  : Wrel1;
        const float* W = (seg == 0) ? Wroot : (Wrel + (size_t)(seg - 1) * 128 * 128);
        unsigned short* dst = Wp + (size_t)tid * 8;
        #pragma unroll
        for (int j = 0; j < 8; ++j)
            dst[j] = f2h(W[(size_t)(kl + j) * 128 + chan]);
    } else {
        int e = (bid - CVT_BLOCKS - PACK_BLOCKS) * 256 + threadIdx.x;
        if (e >= N_EDGES) return;
        int dst = ei[N_EDGES + e];
        int r = et[e];
        atomicAdd(cnt + (size_t)r * N_NODES + dst, 1u);
    }
}

// ---------------------------------------------------------------------------
// Scan chain for CSR row starts (scan1 -> scan3; scan2 folded into scan3)
// ---------------------------------------------------------------------------
__global__ __launch_bounds__(256) void scan1_kernel(
    const unsigned* __restrict__ cnt,
    unsigned* __restrict__ rs, unsigned* __restrict__ bsums)
{
    __shared__ unsigned sdata[256];
    int t = threadIdx.x;
    int base = blockIdx.x * SCAN_BLK + t * 4;
    unsigned v[4]; unsigned s = 0;
    #pragma unroll
    for (int j = 0; j < 4; ++j) {
        v[j] = (base + j < M_SEG) ? cnt[base + j] : 0u;
        s += v[j];
    }
    sdata[t] = s;
    __syncthreads();
    #pragma unroll
    for (int off = 1; off < 256; off <<= 1) {
        unsigned x = (t >= off) ? sdata[t - off] : 0u;
        __syncthreads();
        if (t >= off) sdata[t] += x;
        __syncthreads();
    }
    unsigned excl = (t > 0) ? sdata[t - 1] : 0u;
    if (t == 255) bsums[blockIdx.x] = sdata[255];
    unsigned run = excl;
    #pragma unroll
    for (int j = 0; j < 4; ++j) {
        if (base + j < M_SEG) rs[base + j] = run;
        run += v[j];
    }
}

// scan3: each block redundantly scans the 196 block sums in LDS (trivial),
// then applies the offset.  Removes the serial single-block scan2 dispatch.
__global__ __launch_bounds__(256) void scan3_kernel(
    unsigned* __restrict__ rs, const unsigned* __restrict__ bsums,
    unsigned* __restrict__ cursor)
{
    __shared__ unsigned sdata[256];
    int t = threadIdx.x;
    sdata[t] = (t < SCAN_NB) ? bsums[t] : 0u;
    __syncthreads();
    #pragma unroll
    for (int off = 1; off < 256; off <<= 1) {
        unsigned x = (t >= off) ? sdata[t - off] : 0u;
        __syncthreads();
        if (t >= off) sdata[t] += x;
        __syncthreads();
    }
    int i = blockIdx.x * blockDim.x + t;
    if (i < M_SEG) {
        int b = i >> 10;
        unsigned add = (b > 0) ? sdata[b - 1] : 0u;
        unsigned v = rs[i] + add;
        rs[i] = v;
        cursor[i] = v;
    }
    if (i == 0) rs[M_SEG] = N_EDGES;
}

__global__ __launch_bounds__(256) void fill_kernel(
    const int* __restrict__ ei, const int* __restrict__ et,
    unsigned* __restrict__ cursor, unsigned* __restrict__ csr)
{
    int e = blockIdx.x * blockDim.x + threadIdx.x;
    if (e >= N_EDGES) return;
    int src = ei[e];
    int dst = ei[N_EDGES + e];
    int r = et[e];
    unsigned pos = atomicAdd(cursor + (size_t)r * N_NODES + dst, 1u);
    csr[pos] = (unsigned)src;
}

// ---------------------------------------------------------------------------
// Fused gather + MFMA GEMM (fp16) with VGPR-free async LDS gather (round 7)
// plus DEPTH-2 B prefetch in the MFMA phase:
//  * gather: per (wave, rel) contiguous edge run pulled by up to 12
//    global_load_lds (per-lane global addr, linear LDS dest, XOR-swizzled on
//    both sides), one vmcnt(0) + sched_barrier, per-lane LDS accumulation.
//  * MFMA: bb[3] ring prefetches B for ks+2 while computing ks — two full
//    iterations (~320 cyc) cover the ~225-cyc L2 latency that the old
//    depth-1 ping-pong exposed every K-step.  ax[4] fully preloaded.
//  * 256 threads, default launch bounds (forced bounds spilled in r4/r5).
// ---------------------------------------------------------------------------
template <bool FINAL>
__global__ __launch_bounds__(256) void gemm_kernel(
    const unsigned short* __restrict__ Xin,   // [PAD_N][128] fp16 (layer input + gather source)
    const unsigned* __restrict__ rs,          // [M_SEG+1] CSR row starts
    const unsigned* __restrict__ csr,         // [N_EDGES] src node per slot
    const unsigned short* __restrict__ Wp,    // packed [12][8][64][8] fp16
    const float* __restrict__ bias,           // [128] fp32
    unsigned short* __restrict__ Hout,        // [PAD_N][128] fp16 (!FINAL)
    const float* __restrict__ Wc,             // [128][2] fp32 (FINAL)
    const float* __restrict__ bc,             // [2] fp32 (FINAL)
    float* __restrict__ Out)                  // [N][2] fp32 (FINAL)
{
    __shared__ __align__(16) unsigned char gbuf[4][GB_EDGES * 256];   // 48 KB

    const int t    = threadIdx.x;
    const int w    = t >> 6;          // wave 0..3
    const int lane = t & 63;
    const int l15  = lane & 15;
    const int quad = lane >> 4;
    const int rowbase = blockIdx.x * 64 + w * 16;   // this wave's 16 nodes
    const int koff = quad * 8;
    unsigned char* myBuf = &gbuf[w][0];

    const uint4* __restrict__ X4 = (const uint4*)Xin;   // 16B units

    // ---- per-lane accumulators for the 2 relation means ----
    __half2 a2[2][4][4];              // [r][ksl][j] — statically indexed
    #pragma unroll
    for (int r = 0; r < 2; ++r)
        #pragma unroll
        for (int ksl = 0; ksl < 4; ++ksl)
            #pragma unroll
            for (int j = 0; j < 4; ++j)
                a2[r][ksl][j] = __float2half2_rn(0.f);

    const int node = rowbase + l15;
    float inv_[2] = {1.f, 1.f};

    if (rowbase < N_NODES) {          // 16-row windows are fully real or fully pad
        #pragma unroll
        for (int r = 0; r < 2; ++r) {
            // wave-uniform edge run for the window; per-lane node bounds
            unsigned S = rs[(size_t)r * N_NODES + rowbase];
            unsigned E = rs[(size_t)r * N_NODES + rowbase + 16];
            unsigned st = rs[(size_t)r * N_NODES + node];
            unsigned en = rs[(size_t)r * N_NODES + node + 1];
            unsigned d = en - st;
            inv_[r] = 1.0f / (float)(d ? d : 1u);

            for (unsigned base = S; base < E; base += GB_EDGES) {
                unsigned cnt = E - base;
                if (cnt > GB_EDGES) cnt = GB_EDGES;

                // 1) per-lane edge IDs for up to 12 gather instructions
                unsigned ids[12];
                #pragma unroll
                for (int i = 0; i < 12; ++i) {
                    if ((unsigned)(i * 4) < cnt) {
                        unsigned e = base + (unsigned)(i * 4) + (unsigned)(lane >> 4);
                        ids[i] = csr[e < E ? e : E - 1u];
                    } else ids[i] = 0u;
                }

                // 2) async gather: 4 edge-rows x 16 chunks per instruction,
                //    per-lane global source, linear LDS dest, src swizzled
                #pragma unroll
                for (int i = 0; i < 12; ++i) {
                    if ((unsigned)(i * 4) < cnt) {
                        unsigned eL = (unsigned)(i * 4) + (unsigned)(lane >> 4);
                        unsigned cg = (unsigned)(lane & 15) ^ (eL & 7u);
                        const unsigned short* gp =
                            (const unsigned short*)(X4 + ((size_t)ids[i] << 4) + cg);
                        __builtin_amdgcn_global_load_lds(
                            (const __attribute__((address_space(1))) unsigned int*)gp,
                            (__attribute__((address_space(3))) unsigned int*)(myBuf + i * 1024),
                            16, 0, 0);
                    }
                }

                asm volatile("s_waitcnt vmcnt(0)" ::: "memory");
                __builtin_amdgcn_sched_barrier(0);

                // 3) per-lane accumulation of its node's rows in this batch
                unsigned lo = st > base ? st : base;
                unsigned hiB = base + cnt;
                unsigned hi = en < hiB ? en : hiB;
                for (unsigned p = lo; p < hi; ++p) {
                    unsigned eL = p - base;
                    const unsigned char* rowb = myBuf + eL * 256;
                    #pragma unroll
                    for (int ksl = 0; ksl < 4; ++ksl) {
                        unsigned pos = ((unsigned)(ksl * 4 + quad)) ^ (eL & 7u);
                        half8 h = *(const half8*)(rowb + pos * 16);
                        #pragma unroll
                        for (int j = 0; j < 4; ++j)
                            a2[r][ksl][j] = __hadd2(a2[r][ksl][j],
                                                    ((const __half2*)&h)[j]);
                    }
                }
            }
        }
    }

    // scale to means
    half8 ag[2][4];                   // [r][ksl]
    #pragma unroll
    for (int r = 0; r < 2; ++r) {
        __half2 s2 = __float2half2_rn(inv_[r]);
        #pragma unroll
        for (int ksl = 0; ksl < 4; ++ksl) {
            half8 h;
            #pragma unroll
            for (int j = 0; j < 4; ++j)
                ((__half2*)&h)[j] = __hmul2(a2[r][ksl][j], s2);
            ag[r][ksl] = h;
        }
    }

    // ---- MFMA phase: B from L2 with DEPTH-2 ring prefetch; ax preloaded ----
    auto ldB = [&](int ks, int nt) -> half8 {
        return *(const half8*)(Wp + ((size_t)(ks * 8 + nt) * 64 + lane) * 8);
    };
    const unsigned short* aBase = Xin + (size_t)(rowbase + l15) * 128 + koff;

    float4v acc[8];
    #pragma unroll
    for (int nt = 0; nt < 8; ++nt) {
        float bv = bias[nt * 16 + l15];
        acc[nt] = float4v{bv, bv, bv, bv};
    }

    half8 ax[4];
    #pragma unroll
    for (int ksl = 0; ksl < 4; ++ksl)
        ax[ksl] = *(const half8*)(aBase + ksl * 32);

    half8 bb[3][8];                   // ring, ks%3 is compile-time under unroll
    #pragma unroll
    for (int nt = 0; nt < 8; ++nt) bb[0][nt] = ldB(0, nt);
    #pragma unroll
    for (int nt = 0; nt < 8; ++nt) bb[1][nt] = ldB(1, nt);

    #pragma unroll
    for (int ks = 0; ks < 12; ++ks) {
        if (ks + 2 < 12) {
            #pragma unroll
            for (int nt = 0; nt < 8; ++nt)
                bb[(ks + 2) % 3][nt] = ldB(ks + 2, nt);
        }
        half8 A = (ks < 4) ? ax[ks] : ag[(ks >> 2) - 1][ks & 3];
        #pragma unroll
        for (int nt = 0; nt < 8; ++nt)
            acc[nt] = __builtin_amdgcn_mfma_f32_16x16x32_f16(A, bb[ks % 3][nt], acc[nt], 0, 0, 0);
    }

    if (!FINAL) {
        // D layout: row = quad*4 + rr, col = l15 (within each 16x16 tile)
        #pragma unroll
        for (int rr = 0; rr < 4; ++rr) {
            int n2 = rowbase + quad * 4 + rr;
            unsigned short* hp = Hout + (size_t)n2 * 128 + l15;
            #pragma unroll
            for (int nt = 0; nt < 8; ++nt)
                hp[nt * 16] = f2h(fmaxf(acc[nt][rr], 0.f));
        }
    } else {
        float wc0[8], wc1[8];
        #pragma unroll
        for (int nt = 0; nt < 8; ++nt) {
            wc0[nt] = Wc[(nt * 16 + l15) * 2 + 0];
            wc1[nt] = Wc[(nt * 16 + l15) * 2 + 1];
        }
        float b0 = bc[0], b1 = bc[1];
        #pragma unroll
        for (int rr = 0; rr < 4; ++rr) {
            float l0 = 0.f, l1 = 0.f;
            #pragma unroll
            for (int nt = 0; nt < 8; ++nt) {
                float h = fmaxf(acc[nt][rr], 0.f);
                l0 += h * wc0[nt];
                l1 += h * wc1[nt];
            }
            #pragma unroll
            for (int off = 8; off > 0; off >>= 1) {
                l0 += __shfl_down(l0, off, 16);
                l1 += __shfl_down(l1, off, 16);
            }
            int n2 = rowbase + quad * 4 + rr;
            if (l15 == 0 && n2 < N_NODES) {
                Out[(size_t)n2 * 2 + 0] = l0 + b0;
                Out[(size_t)n2 * 2 + 1] = l1 + b1;
            }
        }
    }
}

extern "C" void kernel_launch(void* const* d_in, const int* in_sizes, int n_in,
                              void* d_out, int out_size, void* d_ws, size_t ws_size,
                              hipStream_t stream)
{
    const float* x      = (const float*)d_in[0];
    const int*   ei     = (const int*)d_in[1];
    const int*   et     = (const int*)d_in[2];
    const float* Wrel1  = (const float*)d_in[3];
    const float* Wroot1 = (const float*)d_in[4];
    const float* b1     = (const float*)d_in[5];
    const float* Wrel2  = (const float*)d_in[6];
    const float* Wroot2 = (const float*)d_in[7];
    const float* b2     = (const float*)d_in[8];
    const float* Wc     = (const float*)d_in[9];
    const float* bc     = (const float*)d_in[10];
    float* out = (float*)d_out;

    char* ws = (char*)d_ws;
    size_t off = 0;
    auto alloc = [&](size_t bytes) {
        void* p = ws + off;
        off += (bytes + 255) & ~(size_t)255;
        return p;
    };
    unsigned short* xb    = (unsigned short*)alloc((size_t)PAD_N * IN_DIM * 2);
    unsigned short* h1b   = (unsigned short*)alloc((size_t)PAD_N * HID * 2);
    unsigned short* Wp    = (unsigned short*)alloc((size_t)2 * 12 * 8 * 64 * 8 * 2);
    unsigned*       rs    = (unsigned*)alloc((size_t)(M_SEG + 1) * 4);
    unsigned*       cursor= (unsigned*)alloc((size_t)M_SEG * 4);
    unsigned*       bsums = (unsigned*)alloc(256 * 4);
    unsigned*       csr   = (unsigned*)alloc((size_t)N_EDGES * 4);

    const int edge_blocks = (N_EDGES + 255) / 256;
    const int seg_blocks  = (M_SEG + 255) / 256;
    const int gemm_blocks = PAD_N / 64;                 // 1564
    const int prep_blocks = CVT_BLOCKS + PACK_BLOCKS + HIST_BLOCKS;

    // ---- CSR build + conversions (graph identical for both layers) ----
    hipMemsetAsync(cursor, 0, (size_t)M_SEG * 4, stream);
    prep_kernel<<<prep_blocks, 256, 0, stream>>>(
        x, xb, Wroot1, Wrel1, Wroot2, Wrel2, Wp, ei, et, cursor);
    scan1_kernel<<<SCAN_NB, 256, 0, stream>>>(cursor, rs, bsums);
    scan3_kernel<<<seg_blocks, 256, 0, stream>>>(rs, bsums, cursor);
    fill_kernel<<<edge_blocks, 256, 0, stream>>>(ei, et, cursor, csr);

    // ---- layer 1 (fused gather+gemm) ----
    gemm_kernel<false><<<gemm_blocks, 256, 0, stream>>>(
        xb, rs, csr, Wp, b1, h1b, nullptr, nullptr, nullptr);

    // ---- layer 2 (fused gather+gemm, FINAL classifier) ----
    gemm_kernel<true><<<gemm_blocks, 256, 0, stream>>>(
        h1b, rs, csr, Wp + (size_t)12 * 8 * 64 * 8, b2, nullptr, Wc, bc, out);
}

// Round 10
// 257.849 us; speedup vs baseline: 1.1437x; 1.1063x over previous
//
#include <hip/hip_runtime.h>
#include <hip/hip_fp16.h>

#define N_NODES 100000
#define PAD_N   100096                   // 782 * 128, padded M for GEMM tiles
#define IN_DIM 128
#define HID 128
#define N_REL 2
#define N_EDGES 500000
#define M_SEG (N_REL * N_NODES)          // 200000 (rel,node) segments
#define SCAN_BLK 1024
#define SCAN_NB ((M_SEG + SCAN_BLK - 1) / SCAN_BLK)   // 196

#define CVT_BLOCKS 12500                 // N_NODES*IN_DIM/4 / 256
#define PACK_BLOCKS 48                   // 2*12*8*64 / 256
#define HIST_BLOCKS 1954                 // ceil(N_EDGES/256)

#define GB_EDGES 48                      // gather batch: 48 edge-rows (12 KB/wave)

typedef __attribute__((ext_vector_type(8))) _Float16 half8;
typedef __attribute__((ext_vector_type(4))) float float4v;

__device__ __forceinline__ unsigned short f2h(float f) {
    return __half_as_ushort(__float2half(f));   // RNE
}

// ---------------------------------------------------------------------------
// Fused prep: cvt (x fp32->fp16) | pack (weights->B-frag order, fp16) | hist.
// Layer-1 pack uses PERMUTED channel order chan = l15*8 + nt so the gemm
// epilogue can write H with coalesced half8 stores while H memory stays in
// TRUE channel order (layer 2 needs no changes).  Layer-2 pack unchanged.
// ---------------------------------------------------------------------------
__global__ __launch_bounds__(256) void prep_kernel(
    const float* __restrict__ X, unsigned short* __restrict__ Xb,
    const float* __restrict__ Wroot1, const float* __restrict__ Wrel1,
    const float* __restrict__ Wroot2, const float* __restrict__ Wrel2,
    unsigned short* __restrict__ Wp,
    const int* __restrict__ ei, const int* __restrict__ et,
    unsigned* __restrict__ cnt)
{
    int bid = blockIdx.x;
    if (bid < CVT_BLOCKS) {
        int i = bid * 256 + threadIdx.x;
        if (i >= N_NODES * IN_DIM / 4) return;
        float4 v = ((const float4*)X)[i];
        ushort4 o;
        o.x = f2h(v.x); o.y = f2h(v.y); o.z = f2h(v.z); o.w = f2h(v.w);
        ((ushort4*)Xb)[i] = o;
    } else if (bid < CVT_BLOCKS + PACK_BLOCKS) {
        int tid = (bid - CVT_BLOCKS) * 256 + threadIdx.x;
        int layer = tid / 6144;
        int rem   = tid % 6144;
        int ks    = rem / 512;
        int rem2  = rem % 512;
        int nt    = rem2 / 64;
        int lane  = rem2 % 64;
        int seg = ks >> 2;
        int kl  = (ks & 3) * 32 + (lane >> 4) * 8;
        // layer 0: permuted N-channel order (coalesced H store); layer 1: MFMA order
        int chan = layer ? (nt * 16 + (lane & 15)) : ((lane & 15) * 8 + nt);
        const float* Wroot = layer ? Wroot2 : Wroot1;
        const float* Wrel  = layer ? Wrel2  : Wrel1;
        const float* W = (seg == 0) ? Wroot : (Wrel + (size_t)(seg - 1) * 128 * 128);
        unsigned short* dst = Wp + (size_t)tid * 8;
        #pragma unroll
        for (int j = 0; j < 8; ++j)
            dst[j] = f2h(W[(size_t)(kl + j) * 128 + chan]);
    } else {
        int e = (bid - CVT_BLOCKS - PACK_BLOCKS) * 256 + threadIdx.x;
        if (e >= N_EDGES) return;
        int dst = ei[N_EDGES + e];
        int r = et[e];
        atomicAdd(cnt + (size_t)r * N_NODES + dst, 1u);
    }
}

// ---------------------------------------------------------------------------
// Scan chain for CSR row starts (scan1 -> scan3; scan2 folded into scan3)
// ---------------------------------------------------------------------------
__global__ __launch_bounds__(256) void scan1_kernel(
    const unsigned* __restrict__ cnt,
    unsigned* __restrict__ rs, unsigned* __restrict__ bsums)
{
    __shared__ unsigned sdata[256];
    int t = threadIdx.x;
    int base = blockIdx.x * SCAN_BLK + t * 4;
    unsigned v[4]; unsigned s = 0;
    #pragma unroll
    for (int j = 0; j < 4; ++j) {
        v[j] = (base + j < M_SEG) ? cnt[base + j] : 0u;
        s += v[j];
    }
    sdata[t] = s;
    __syncthreads();
    #pragma unroll
    for (int off = 1; off < 256; off <<= 1) {
        unsigned x = (t >= off) ? sdata[t - off] : 0u;
        __syncthreads();
        if (t >= off) sdata[t] += x;
        __syncthreads();
    }
    unsigned excl = (t > 0) ? sdata[t - 1] : 0u;
    if (t == 255) bsums[blockIdx.x] = sdata[255];
    unsigned run = excl;
    #pragma unroll
    for (int j = 0; j < 4; ++j) {
        if (base + j < M_SEG) rs[base + j] = run;
        run += v[j];
    }
}

// scan3: each block redundantly scans the 196 block sums in LDS (trivial),
// then applies the offset.  Removes the serial single-block scan2 dispatch.
__global__ __launch_bounds__(256) void scan3_kernel(
    unsigned* __restrict__ rs, const unsigned* __restrict__ bsums,
    unsigned* __restrict__ cursor)
{
    __shared__ unsigned sdata[256];
    int t = threadIdx.x;
    sdata[t] = (t < SCAN_NB) ? bsums[t] : 0u;
    __syncthreads();
    #pragma unroll
    for (int off = 1; off < 256; off <<= 1) {
        unsigned x = (t >= off) ? sdata[t - off] : 0u;
        __syncthreads();
        if (t >= off) sdata[t] += x;
        __syncthreads();
    }
    int i = blockIdx.x * blockDim.x + t;
    if (i < M_SEG) {
        int b = i >> 10;
        unsigned add = (b > 0) ? sdata[b - 1] : 0u;
        unsigned v = rs[i] + add;
        rs[i] = v;
        cursor[i] = v;
    }
    if (i == 0) rs[M_SEG] = N_EDGES;
}

__global__ __launch_bounds__(256) void fill_kernel(
    const int* __restrict__ ei, const int* __restrict__ et,
    unsigned* __restrict__ cursor, unsigned* __restrict__ csr)
{
    int e = blockIdx.x * blockDim.x + threadIdx.x;
    if (e >= N_EDGES) return;
    int src = ei[e];
    int dst = ei[N_EDGES + e];
    int r = et[e];
    unsigned pos = atomicAdd(cursor + (size_t)r * N_NODES + dst, 1u);
    csr[pos] = (unsigned)src;
}

// ---------------------------------------------------------------------------
// Fused gather + MFMA GEMM (fp16), VMEM-issue-optimized:
//  * Theory: all variants are TA/address-throughput bound (~150 vmem
//    instrs/wave: 10 scattered gather-lds + 96 direct 1KB B loads + 32
//    strided H stores).  This version cuts that ~3x:
//    - B staged through LDS with the R0 2x24KB double-buffer (24
//      global_load_lds per BLOCK per phase = 6/wave amortized; reads move
//      to the separate LDS pipe as ds_read_b128).
//    - the SAME 48 KB LDS is reused: async gather (R7 body) runs first in
//      it, then one barrier, then it becomes the B double-buffer ->
//      occupancy stays 3 blocks/CU.
//    - H store: layer-1 channels permuted in Wp so each lane's 8 acc values
//      are 8 consecutive channels -> 4 coalesced half8 stores (vs 32
//      strided 2-B stores); H memory remains true channel order.
//  * 256 threads, default launch bounds (forced bounds spilled in r4/r5).
// ---------------------------------------------------------------------------
template <bool FINAL>
__global__ __launch_bounds__(256) void gemm_kernel(
    const unsigned short* __restrict__ Xin,   // [PAD_N][128] fp16 (layer input + gather source)
    const unsigned* __restrict__ rs,          // [M_SEG+1] CSR row starts
    const unsigned* __restrict__ csr,         // [N_EDGES] src node per slot
    const unsigned short* __restrict__ Wp,    // packed [12][8][64][8] fp16
    const float* __restrict__ bias,           // [128] fp32
    unsigned short* __restrict__ Hout,        // [PAD_N][128] fp16 (!FINAL)
    const float* __restrict__ Wc,             // [128][2] fp32 (FINAL)
    const float* __restrict__ bc,             // [2] fp32 (FINAL)
    float* __restrict__ Out)                  // [N][2] fp32 (FINAL)
{
    // 48 KB, time-shared: gather buffers (4 x 12 KB) then B dbuf (2 x 24 KB)
    __shared__ __align__(16) unsigned char lds_raw[49152];

    const int t    = threadIdx.x;
    const int w    = t >> 6;          // wave 0..3
    const int lane = t & 63;
    const int l15  = lane & 15;
    const int quad = lane >> 4;
    const int rowbase = blockIdx.x * 64 + w * 16;   // this wave's 16 nodes
    const int koff = quad * 8;
    unsigned char* myBuf = lds_raw + w * (GB_EDGES * 256);
    unsigned short* ldsB = (unsigned short*)lds_raw;   // [2][3*8*512]

    const uint4* __restrict__ X4 = (const uint4*)Xin;   // 16B units

    // ---- seg-0 A-frags preloaded (latency hides under the gather) ----
    const unsigned short* aBase = Xin + (size_t)(rowbase + l15) * 128 + koff;
    half8 ax[4];
    #pragma unroll
    for (int ksl = 0; ksl < 4; ++ksl)
        ax[ksl] = *(const half8*)(aBase + ksl * 32);

    // ---- per-lane accumulators for the 2 relation means ----
    __half2 a2[2][4][4];              // [r][ksl][j] — statically indexed
    #pragma unroll
    for (int r = 0; r < 2; ++r)
        #pragma unroll
        for (int ksl = 0; ksl < 4; ++ksl)
            #pragma unroll
            for (int j = 0; j < 4; ++j)
                a2[r][ksl][j] = __float2half2_rn(0.f);

    const int node = rowbase + l15;
    float inv_[2] = {1.f, 1.f};

    if (rowbase < N_NODES) {          // 16-row windows are fully real or fully pad
        #pragma unroll
        for (int r = 0; r < 2; ++r) {
            // wave-uniform edge run for the window; per-lane node bounds
            unsigned S = rs[(size_t)r * N_NODES + rowbase];
            unsigned E = rs[(size_t)r * N_NODES + rowbase + 16];
            unsigned st = rs[(size_t)r * N_NODES + node];
            unsigned en = rs[(size_t)r * N_NODES + node + 1];
            unsigned d = en - st;
            inv_[r] = 1.0f / (float)(d ? d : 1u);

            for (unsigned base = S; base < E; base += GB_EDGES) {
                unsigned cnt = E - base;
                if (cnt > GB_EDGES) cnt = GB_EDGES;

                // 1) per-lane edge IDs for up to 12 gather instructions
                unsigned ids[12];
                #pragma unroll
                for (int i = 0; i < 12; ++i) {
                    if ((unsigned)(i * 4) < cnt) {
                        unsigned e = base + (unsigned)(i * 4) + (unsigned)(lane >> 4);
                        ids[i] = csr[e < E ? e : E - 1u];
                    } else ids[i] = 0u;
                }

                // 2) async gather: 4 edge-rows x 16 chunks per instruction,
                //    per-lane global source, linear LDS dest, src swizzled
                #pragma unroll
                for (int i = 0; i < 12; ++i) {
                    if ((unsigned)(i * 4) < cnt) {
                        unsigned eL = (unsigned)(i * 4) + (unsigned)(lane >> 4);
                        unsigned cg = (unsigned)(lane & 15) ^ (eL & 7u);
                        const unsigned short* gp =
                            (const unsigned short*)(X4 + ((size_t)ids[i] << 4) + cg);
                        __builtin_amdgcn_global_load_lds(
                            (const __attribute__((address_space(1))) unsigned int*)gp,
                            (__attribute__((address_space(3))) unsigned int*)(myBuf + i * 1024),
                            16, 0, 0);
                    }
                }

                asm volatile("s_waitcnt vmcnt(0)" ::: "memory");
                __builtin_amdgcn_sched_barrier(0);

                // 3) per-lane accumulation of its node's rows in this batch
                unsigned lo = st > base ? st : base;
                unsigned hiB = base + cnt;
                unsigned hi = en < hiB ? en : hiB;
                for (unsigned p = lo; p < hi; ++p) {
                    unsigned eL = p - base;
                    const unsigned char* rowb = myBuf + eL * 256;
                    #pragma unroll
                    for (int ksl = 0; ksl < 4; ++ksl) {
                        unsigned pos = ((unsigned)(ksl * 4 + quad)) ^ (eL & 7u);
                        half8 h = *(const half8*)(rowb + pos * 16);
                        #pragma unroll
                        for (int j = 0; j < 4; ++j)
                            a2[r][ksl][j] = __hadd2(a2[r][ksl][j],
                                                    ((const __half2*)&h)[j]);
                    }
                }
            }
        }
    }

    // scale to means
    half8 ag[2][4];                   // [r][ksl]
    #pragma unroll
    for (int r = 0; r < 2; ++r) {
        __half2 s2 = __float2half2_rn(inv_[r]);
        #pragma unroll
        for (int ksl = 0; ksl < 4; ++ksl) {
            half8 h;
            #pragma unroll
            for (int j = 0; j < 4; ++j)
                ((__half2*)&h)[j] = __hmul2(a2[r][ksl][j], s2);
            ag[r][ksl] = h;
        }
    }

    __syncthreads();                  // all waves done with gather LDS

    // ---- MFMA phase: B double-buffered in LDS (R0 pattern, 6 stages/wave) ----
    auto stage = [&](int ph, int buf) {
        #pragma unroll
        for (int fi = 0; fi < 6; ++fi) {
            int f  = fi * 4 + w;          // 0..23
            int sl = f >> 3;              // phase-local K-step 0..2
            int nt = f & 7;
            int ks = ph * 3 + sl;
            const unsigned short* g = Wp + ((size_t)(ks * 8 + nt) * 64 + lane) * 8;
            unsigned short* l = ldsB + (size_t)buf * 12288 + (size_t)(sl * 8 + nt) * 512;
            __builtin_amdgcn_global_load_lds(
                (const __attribute__((address_space(1))) unsigned int*)g,
                (__attribute__((address_space(3))) unsigned int*)l, 16, 0, 0);
        }
    };

    float4v acc[8];
    #pragma unroll
    for (int nt = 0; nt < 8; ++nt) {
        float bv = FINAL ? bias[nt * 16 + l15] : bias[l15 * 8 + nt];
        acc[nt] = float4v{bv, bv, bv, bv};
    }

    stage(0, 0);
    __syncthreads();                  // phase-0 B staged (vmcnt drained)

    #pragma unroll
    for (int ph = 0; ph < 4; ++ph) {
        if (ph < 3) stage(ph + 1, (ph + 1) & 1);   // overlap staging with compute
        #pragma unroll
        for (int sl = 0; sl < 3; ++sl) {
            int ks = ph * 3 + sl;
            half8 b[8];
            #pragma unroll
            for (int nt = 0; nt < 8; ++nt)
                b[nt] = *(const half8*)(ldsB + (size_t)(ph & 1) * 12288 +
                                        (size_t)(sl * 8 + nt) * 512 + lane * 8);
            half8 A = (ks < 4) ? ax[ks] : ag[(ks >> 2) - 1][ks & 3];
            #pragma unroll
            for (int nt = 0; nt < 8; ++nt)
                acc[nt] = __builtin_amdgcn_mfma_f32_16x16x32_f16(A, b[nt], acc[nt], 0, 0, 0);
        }
        __syncthreads();   // readers done with buf(ph&1); stage(ph+1) drained
    }

    if (!FINAL) {
        // Permuted channels: lane's acc[0..7][rr] = channels l15*8 .. l15*8+7
        // of node rowbase + quad*4 + rr -> one coalesced half8 store per rr.
        #pragma unroll
        for (int rr = 0; rr < 4; ++rr) {
            int n2 = rowbase + quad * 4 + rr;
            __half2 hv[4];
            #pragma unroll
            for (int j = 0; j < 4; ++j)
                hv[j] = __floats2half2_rn(fmaxf(acc[2 * j][rr], 0.f),
                                          fmaxf(acc[2 * j + 1][rr], 0.f));
            *(uint4*)(Hout + (size_t)n2 * 128 + l15 * 8) = *(const uint4*)hv;
        }
    } else {
        float wc0[8], wc1[8];
        #pragma unroll
        for (int nt = 0; nt < 8; ++nt) {
            wc0[nt] = Wc[(nt * 16 + l15) * 2 + 0];
            wc1[nt] = Wc[(nt * 16 + l15) * 2 + 1];
        }
        float b0 = bc[0], b1 = bc[1];
        #pragma unroll
        for (int rr = 0; rr < 4; ++rr) {
            float l0 = 0.f, l1 = 0.f;
            #pragma unroll
            for (int nt = 0; nt < 8; ++nt) {
                float h = fmaxf(acc[nt][rr], 0.f);
                l0 += h * wc0[nt];
                l1 += h * wc1[nt];
            }
            #pragma unroll
            for (int off = 8; off > 0; off >>= 1) {
                l0 += __shfl_down(l0, off, 16);
                l1 += __shfl_down(l1, off, 16);
            }
            int n2 = rowbase + quad * 4 + rr;
            if (l15 == 0 && n2 < N_NODES) {
                Out[(size_t)n2 * 2 + 0] = l0 + b0;
                Out[(size_t)n2 * 2 + 1] = l1 + b1;
            }
        }
    }
}

extern "C" void kernel_launch(void* const* d_in, const int* in_sizes, int n_in,
                              void* d_out, int out_size, void* d_ws, size_t ws_size,
                              hipStream_t stream)
{
    const float* x      = (const float*)d_in[0];
    const int*   ei     = (const int*)d_in[1];
    const int*   et     = (const int*)d_in[2];
    const float* Wrel1  = (const float*)d_in[3];
    const float* Wroot1 = (const float*)d_in[4];
    const float* b1     = (const float*)d_in[5];
    const float* Wrel2  = (const float*)d_in[6];
    const float* Wroot2 = (const float*)d_in[7];
    const float* b2     = (const float*)d_in[8];
    const float* Wc     = (const float*)d_in[9];
    const float* bc     = (const float*)d_in[10];
    float* out = (float*)d_out;

    char* ws = (char*)d_ws;
    size_t off = 0;
    auto alloc = [&](size_t bytes) {
        void* p = ws + off;
        off += (bytes + 255) & ~(size_t)255;
        return p;
    };
    unsigned short* xb    = (unsigned short*)alloc((size_t)PAD_N * IN_DIM * 2);
    unsigned short* h1b   = (unsigned short*)alloc((size_t)PAD_N * HID * 2);
    unsigned short* Wp    = (unsigned short*)alloc((size_t)2 * 12 * 8 * 64 * 8 * 2);
    unsigned*       rs    = (unsigned*)alloc((size_t)(M_SEG + 1) * 4);
    unsigned*       cursor= (unsigned*)alloc((size_t)M_SEG * 4);
    unsigned*       bsums = (unsigned*)alloc(256 * 4);
    unsigned*       csr   = (unsigned*)alloc((size_t)N_EDGES * 4);

    const int edge_blocks = (N_EDGES + 255) / 256;
    const int seg_blocks  = (M_SEG + 255) / 256;
    const int gemm_blocks = PAD_N / 64;                 // 1564
    const int prep_blocks = CVT_BLOCKS + PACK_BLOCKS + HIST_BLOCKS;

    // ---- CSR build + conversions (graph identical for both layers) ----
    hipMemsetAsync(cursor, 0, (size_t)M_SEG * 4, stream);
    prep_kernel<<<prep_blocks, 256, 0, stream>>>(
        x, xb, Wroot1, Wrel1, Wroot2, Wrel2, Wp, ei, et, cursor);
    scan1_kernel<<<SCAN_NB, 256, 0, stream>>>(cursor, rs, bsums);
    scan3_kernel<<<seg_blocks, 256, 0, stream>>>(rs, bsums, cursor);
    fill_kernel<<<edge_blocks, 256, 0, stream>>>(ei, et, cursor, csr);

    // ---- layer 1 (fused gather+gemm, LDS-staged B) ----
    gemm_kernel<false><<<gemm_blocks, 256, 0, stream>>>(
        xb, rs, csr, Wp, b1, h1b, nullptr, nullptr, nullptr);

    // ---- layer 2 (fused gather+gemm, FINAL classifier) ----
    gemm_kernel<true><<<gemm_blocks, 256, 0, stream>>>(
        h1b, rs, csr, Wp + (size_t)12 * 8 * 64 * 8, b2, nullptr, Wc, bc, out);
}

// Round 11
// 241.892 us; speedup vs baseline: 1.2192x; 1.0660x over previous
//
#include <hip/hip_runtime.h>
#include <hip/hip_fp16.h>

#define N_NODES 100000
#define PAD_N   100096                   // 782 * 128, padded M for GEMM tiles
#define IN_DIM 128
#define HID 128
#define N_REL 2
#define N_EDGES 500000
#define M_SEG (N_REL * N_NODES)          // 200000 (rel,node) segments
#define SCAN_BLK 1024
#define SCAN_NB ((M_SEG + SCAN_BLK - 1) / SCAN_BLK)   // 196

#define CVT_BLOCKS 12500                 // N_NODES*IN_DIM/4 / 256
#define PACK_BLOCKS 48                   // 2*12*8*64 / 256
#define HIST_BLOCKS 1954                 // ceil(N_EDGES/256)

#define GB_EDGES 48                      // gather batch: 48 edge-rows (12 KB/wave)

typedef __attribute__((ext_vector_type(8))) _Float16 half8;
typedef __attribute__((ext_vector_type(4))) float float4v;

__device__ __forceinline__ unsigned short f2h(float f) {
    return __half_as_ushort(__float2half(f));   // RNE
}

// ---------------------------------------------------------------------------
// Fused prep: cvt (x fp32->fp16) | pack (weights->B-frag order, fp16) | hist.
// Layer-1 pack uses PERMUTED channel order chan = l15*8 + nt so the gemm
// epilogue can write H with coalesced half8 stores while H memory stays in
// TRUE channel order (layer 2 needs no changes).  Layer-2 pack unchanged.
// ---------------------------------------------------------------------------
__global__ __launch_bounds__(256) void prep_kernel(
    const float* __restrict__ X, unsigned short* __restrict__ Xb,
    const float* __restrict__ Wroot1, const float* __restrict__ Wrel1,
    const float* __restrict__ Wroot2, const float* __restrict__ Wrel2,
    unsigned short* __restrict__ Wp,
    const int* __restrict__ ei, const int* __restrict__ et,
    unsigned* __restrict__ cnt)
{
    int bid = blockIdx.x;
    if (bid < CVT_BLOCKS) {
        int i = bid * 256 + threadIdx.x;
        if (i >= N_NODES * IN_DIM / 4) return;
        float4 v = ((const float4*)X)[i];
        ushort4 o;
        o.x = f2h(v.x); o.y = f2h(v.y); o.z = f2h(v.z); o.w = f2h(v.w);
        ((ushort4*)Xb)[i] = o;
    } else if (bid < CVT_BLOCKS + PACK_BLOCKS) {
        int tid = (bid - CVT_BLOCKS) * 256 + threadIdx.x;
        int layer = tid / 6144;
        int rem   = tid % 6144;
        int ks    = rem / 512;
        int rem2  = rem % 512;
        int nt    = rem2 / 64;
        int lane  = rem2 % 64;
        int seg = ks >> 2;
        int kl  = (ks & 3) * 32 + (lane >> 4) * 8;
        // layer 0: permuted N-channel order (coalesced H store); layer 1: MFMA order
        int chan = layer ? (nt * 16 + (lane & 15)) : ((lane & 15) * 8 + nt);
        const float* Wroot = layer ? Wroot2 : Wroot1;
        const float* Wrel  = layer ? Wrel2  : Wrel1;
        const float* W = (seg == 0) ? Wroot : (Wrel + (size_t)(seg - 1) * 128 * 128);
        unsigned short* dst = Wp + (size_t)tid * 8;
        #pragma unroll
        for (int j = 0; j < 8; ++j)
            dst[j] = f2h(W[(size_t)(kl + j) * 128 + chan]);
    } else {
        int e = (bid - CVT_BLOCKS - PACK_BLOCKS) * 256 + threadIdx.x;
        if (e >= N_EDGES) return;
        int dst = ei[N_EDGES + e];
        int r = et[e];
        atomicAdd(cnt + (size_t)r * N_NODES + dst, 1u);
    }
}

// ---------------------------------------------------------------------------
// Scan chain for CSR row starts (scan1 -> scan3; scan2 folded into scan3)
// ---------------------------------------------------------------------------
__global__ __launch_bounds__(256) void scan1_kernel(
    const unsigned* __restrict__ cnt,
    unsigned* __restrict__ rs, unsigned* __restrict__ bsums)
{
    __shared__ unsigned sdata[256];
    int t = threadIdx.x;
    int base = blockIdx.x * SCAN_BLK + t * 4;
    unsigned v[4]; unsigned s = 0;
    #pragma unroll
    for (int j = 0; j < 4; ++j) {
        v[j] = (base + j < M_SEG) ? cnt[base + j] : 0u;
        s += v[j];
    }
    sdata[t] = s;
    __syncthreads();
    #pragma unroll
    for (int off = 1; off < 256; off <<= 1) {
        unsigned x = (t >= off) ? sdata[t - off] : 0u;
        __syncthreads();
        if (t >= off) sdata[t] += x;
        __syncthreads();
    }
    unsigned excl = (t > 0) ? sdata[t - 1] : 0u;
    if (t == 255) bsums[blockIdx.x] = sdata[255];
    unsigned run = excl;
    #pragma unroll
    for (int j = 0; j < 4; ++j) {
        if (base + j < M_SEG) rs[base + j] = run;
        run += v[j];
    }
}

// scan3: each block redundantly scans the 196 block sums in LDS (trivial),
// then applies the offset.  Removes the serial single-block scan2 dispatch.
__global__ __launch_bounds__(256) void scan3_kernel(
    unsigned* __restrict__ rs, const unsigned* __restrict__ bsums,
    unsigned* __restrict__ cursor)
{
    __shared__ unsigned sdata[256];
    int t = threadIdx.x;
    sdata[t] = (t < SCAN_NB) ? bsums[t] : 0u;
    __syncthreads();
    #pragma unroll
    for (int off = 1; off < 256; off <<= 1) {
        unsigned x = (t >= off) ? sdata[t - off] : 0u;
        __syncthreads();
        if (t >= off) sdata[t] += x;
        __syncthreads();
    }
    int i = blockIdx.x * blockDim.x + t;
    if (i < M_SEG) {
        int b = i >> 10;
        unsigned add = (b > 0) ? sdata[b - 1] : 0u;
        unsigned v = rs[i] + add;
        rs[i] = v;
        cursor[i] = v;
    }
    if (i == 0) rs[M_SEG] = N_EDGES;
}

__global__ __launch_bounds__(256) void fill_kernel(
    const int* __restrict__ ei, const int* __restrict__ et,
    unsigned* __restrict__ cursor, unsigned* __restrict__ csr)
{
    int e = blockIdx.x * blockDim.x + threadIdx.x;
    if (e >= N_EDGES) return;
    int src = ei[e];
    int dst = ei[N_EDGES + e];
    int r = et[e];
    unsigned pos = atomicAdd(cursor + (size_t)r * N_NODES + dst, 1u);
    csr[pos] = (unsigned)src;
}

// ---------------------------------------------------------------------------
// Fused gather + MFMA GEMM (fp16), VMEM-issue-optimized v2:
//  * R10 base (LDS-staged B dbuf, coalesced H stores) PLUS:
//    - ONE per-lane csr id load per batch (lane L -> csr[S+L], 48 ids in one
//      VMEM op); volley instructions get their 4 ids via __shfl (ds_bpermute,
//      LDS pipe).  Replaces 12 per-lane id loads per batch (-22 VMEM/wave).
//    - both rels' id vectors prefetched up front: rel-1's id load is in
//      flight during rel-0's volley+drain -> one exposed id-latency, not two.
//    - volleys stay sequential (shared 12 KB buffer); lgkmcnt(0)+
//      sched_barrier before each buffer reuse.
//  * 256 threads, default launch bounds (forced bounds spilled in r4/r5).
// ---------------------------------------------------------------------------
template <bool FINAL>
__global__ __launch_bounds__(256) void gemm_kernel(
    const unsigned short* __restrict__ Xin,   // [PAD_N][128] fp16 (layer input + gather source)
    const unsigned* __restrict__ rs,          // [M_SEG+1] CSR row starts
    const unsigned* __restrict__ csr,         // [N_EDGES] src node per slot
    const unsigned short* __restrict__ Wp,    // packed [12][8][64][8] fp16
    const float* __restrict__ bias,           // [128] fp32
    unsigned short* __restrict__ Hout,        // [PAD_N][128] fp16 (!FINAL)
    const float* __restrict__ Wc,             // [128][2] fp32 (FINAL)
    const float* __restrict__ bc,             // [2] fp32 (FINAL)
    float* __restrict__ Out)                  // [N][2] fp32 (FINAL)
{
    // 48 KB, time-shared: gather buffers (4 x 12 KB) then B dbuf (2 x 24 KB)
    __shared__ __align__(16) unsigned char lds_raw[49152];

    const int t    = threadIdx.x;
    const int w    = t >> 6;          // wave 0..3
    const int lane = t & 63;
    const int l15  = lane & 15;
    const int quad = lane >> 4;
    const int rowbase = blockIdx.x * 64 + w * 16;   // this wave's 16 nodes
    const int koff = quad * 8;
    unsigned char* myBuf = lds_raw + w * (GB_EDGES * 256);
    unsigned short* ldsB = (unsigned short*)lds_raw;   // [2][3*8*512]

    const uint4* __restrict__ X4 = (const uint4*)Xin;   // 16B units

    // ---- seg-0 A-frags preloaded (latency hides under the gather) ----
    const unsigned short* aBase = Xin + (size_t)(rowbase + l15) * 128 + koff;
    half8 ax[4];
    #pragma unroll
    for (int ksl = 0; ksl < 4; ++ksl)
        ax[ksl] = *(const half8*)(aBase + ksl * 32);

    // ---- per-lane accumulators for the 2 relation means ----
    __half2 a2[2][4][4];              // [r][ksl][j] — statically indexed
    #pragma unroll
    for (int r = 0; r < 2; ++r)
        #pragma unroll
        for (int ksl = 0; ksl < 4; ++ksl)
            #pragma unroll
            for (int j = 0; j < 4; ++j)
                a2[r][ksl][j] = __float2half2_rn(0.f);

    const int node = rowbase + l15;
    float inv_[2] = {1.f, 1.f};

    // one volley: up to 12 gather-lds; ids taken from idv via shuffle
    auto volley = [&](unsigned idv, unsigned cnt) {
        #pragma unroll
        for (int i = 0; i < 12; ++i) {
            if ((unsigned)(i * 4) < cnt) {
                unsigned id = (unsigned)__shfl((int)idv, i * 4 + (lane >> 4), 64);
                unsigned eL = (unsigned)(i * 4) + (unsigned)(lane >> 4);
                unsigned cg = (unsigned)(lane & 15) ^ (eL & 7u);
                const unsigned short* gp =
                    (const unsigned short*)(X4 + ((size_t)id << 4) + cg);
                __builtin_amdgcn_global_load_lds(
                    (const __attribute__((address_space(1))) unsigned int*)gp,
                    (__attribute__((address_space(3))) unsigned int*)(myBuf + i * 1024),
                    16, 0, 0);
            }
        }
    };

    // accumulate this lane's node rows from the staged batch
    auto accum = [&](int r, unsigned base, unsigned cnt, unsigned st, unsigned en) {
        unsigned lo = st > base ? st : base;
        unsigned hiB = base + cnt;
        unsigned hi = en < hiB ? en : hiB;
        for (unsigned p = lo; p < hi; ++p) {
            unsigned eL = p - base;
            const unsigned char* rowb = myBuf + eL * 256;
            #pragma unroll
            for (int ksl = 0; ksl < 4; ++ksl) {
                unsigned pos = ((unsigned)(ksl * 4 + quad)) ^ (eL & 7u);
                half8 h = *(const half8*)(rowb + pos * 16);
                #pragma unroll
                for (int j = 0; j < 4; ++j)
                    a2[r][ksl][j] = __hadd2(a2[r][ksl][j],
                                            ((const __half2*)&h)[j]);
            }
        }
    };

    if (rowbase < N_NODES) {          // 16-row windows are fully real or fully pad
        // bounds for both rels (wave-uniform S/E; per-lane st/en)
        unsigned S0 = rs[rowbase],               E0 = rs[rowbase + 16];
        unsigned st0 = rs[node],                 en0 = rs[node + 1];
        unsigned S1 = rs[N_NODES + rowbase],     E1 = rs[N_NODES + rowbase + 16];
        unsigned st1 = rs[N_NODES + node],       en1 = rs[N_NODES + node + 1];
        unsigned d0 = en0 - st0; inv_[0] = 1.0f / (float)(d0 ? d0 : 1u);
        unsigned d1 = en1 - st1; inv_[1] = 1.0f / (float)(d1 ? d1 : 1u);

        unsigned c0 = E0 - S0; if (c0 > GB_EDGES) c0 = GB_EDGES;
        unsigned c1 = E1 - S1; if (c1 > GB_EDGES) c1 = GB_EDGES;

        // prefetch BOTH rels' id vectors (one VMEM op each)
        unsigned q0 = S0 + (unsigned)lane;
        unsigned idv0 = (E0 > S0) ? csr[q0 < E0 ? q0 : E0 - 1u] : 0u;
        unsigned q1 = S1 + (unsigned)lane;
        unsigned idv1 = (E1 > S1) ? csr[q1 < E1 ? q1 : E1 - 1u] : 0u;

        volley(idv0, c0);
        asm volatile("s_waitcnt vmcnt(0)" ::: "memory");
        __builtin_amdgcn_sched_barrier(0);
        accum(0, S0, c0, st0, en0);

        asm volatile("s_waitcnt lgkmcnt(0)" ::: "memory");
        __builtin_amdgcn_sched_barrier(0);
        volley(idv1, c1);
        asm volatile("s_waitcnt vmcnt(0)" ::: "memory");
        __builtin_amdgcn_sched_barrier(0);
        accum(1, S1, c1, st1, en1);

        // remainder batches (~10% of windows exceed 48 edges in a rel)
        #pragma unroll
        for (int r = 0; r < 2; ++r) {
            unsigned S  = r ? S1  : S0;
            unsigned E  = r ? E1  : E0;
            unsigned st = r ? st1 : st0;
            unsigned en = r ? en1 : en0;
            for (unsigned base = S + GB_EDGES; base < E; base += GB_EDGES) {
                unsigned cnt = E - base;
                if (cnt > GB_EDGES) cnt = GB_EDGES;
                unsigned q = base + (unsigned)lane;
                unsigned idv = csr[q < E ? q : E - 1u];
                asm volatile("s_waitcnt lgkmcnt(0)" ::: "memory");
                __builtin_amdgcn_sched_barrier(0);
                volley(idv, cnt);
                asm volatile("s_waitcnt vmcnt(0)" ::: "memory");
                __builtin_amdgcn_sched_barrier(0);
                accum(r, base, cnt, st, en);
            }
        }
    }

    // scale to means
    half8 ag[2][4];                   // [r][ksl]
    #pragma unroll
    for (int r = 0; r < 2; ++r) {
        __half2 s2 = __float2half2_rn(inv_[r]);
        #pragma unroll
        for (int ksl = 0; ksl < 4; ++ksl) {
            half8 h;
            #pragma unroll
            for (int j = 0; j < 4; ++j)
                ((__half2*)&h)[j] = __hmul2(a2[r][ksl][j], s2);
            ag[r][ksl] = h;
        }
    }

    __syncthreads();                  // all waves done with gather LDS

    // ---- MFMA phase: B double-buffered in LDS (R0 pattern, 6 stages/wave) ----
    auto stage = [&](int ph, int buf) {
        #pragma unroll
        for (int fi = 0; fi < 6; ++fi) {
            int f  = fi * 4 + w;          // 0..23
            int sl = f >> 3;              // phase-local K-step 0..2
            int nt = f & 7;
            int ks = ph * 3 + sl;
            const unsigned short* g = Wp + ((size_t)(ks * 8 + nt) * 64 + lane) * 8;
            unsigned short* l = ldsB + (size_t)buf * 12288 + (size_t)(sl * 8 + nt) * 512;
            __builtin_amdgcn_global_load_lds(
                (const __attribute__((address_space(1))) unsigned int*)g,
                (__attribute__((address_space(3))) unsigned int*)l, 16, 0, 0);
        }
    };

    float4v acc[8];
    #pragma unroll
    for (int nt = 0; nt < 8; ++nt) {
        float bv = FINAL ? bias[nt * 16 + l15] : bias[l15 * 8 + nt];
        acc[nt] = float4v{bv, bv, bv, bv};
    }

    stage(0, 0);
    __syncthreads();                  // phase-0 B staged (vmcnt drained)

    #pragma unroll
    for (int ph = 0; ph < 4; ++ph) {
        if (ph < 3) stage(ph + 1, (ph + 1) & 1);   // overlap staging with compute
        #pragma unroll
        for (int sl = 0; sl < 3; ++sl) {
            int ks = ph * 3 + sl;
            half8 b[8];
            #pragma unroll
            for (int nt = 0; nt < 8; ++nt)
                b[nt] = *(const half8*)(ldsB + (size_t)(ph & 1) * 12288 +
                                        (size_t)(sl * 8 + nt) * 512 + lane * 8);
            half8 A = (ks < 4) ? ax[ks] : ag[(ks >> 2) - 1][ks & 3];
            #pragma unroll
            for (int nt = 0; nt < 8; ++nt)
                acc[nt] = __builtin_amdgcn_mfma_f32_16x16x32_f16(A, b[nt], acc[nt], 0, 0, 0);
        }
        __syncthreads();   // readers done with buf(ph&1); stage(ph+1) drained
    }

    if (!FINAL) {
        // Permuted channels: lane's acc[0..7][rr] = channels l15*8 .. l15*8+7
        // of node rowbase + quad*4 + rr -> one coalesced half8 store per rr.
        #pragma unroll
        for (int rr = 0; rr < 4; ++rr) {
            int n2 = rowbase + quad * 4 + rr;
            __half2 hv[4];
            #pragma unroll
            for (int j = 0; j < 4; ++j)
                hv[j] = __floats2half2_rn(fmaxf(acc[2 * j][rr], 0.f),
                                          fmaxf(acc[2 * j + 1][rr], 0.f));
            *(uint4*)(Hout + (size_t)n2 * 128 + l15 * 8) = *(const uint4*)hv;
        }
    } else {
        float wc0[8], wc1[8];
        #pragma unroll
        for (int nt = 0; nt < 8; ++nt) {
            wc0[nt] = Wc[(nt * 16 + l15) * 2 + 0];
            wc1[nt] = Wc[(nt * 16 + l15) * 2 + 1];
        }
        float b0 = bc[0], b1 = bc[1];
        #pragma unroll
        for (int rr = 0; rr < 4; ++rr) {
            float l0 = 0.f, l1 = 0.f;
            #pragma unroll
            for (int nt = 0; nt < 8; ++nt) {
                float h = fmaxf(acc[nt][rr], 0.f);
                l0 += h * wc0[nt];
                l1 += h * wc1[nt];
            }
            #pragma unroll
            for (int off = 8; off > 0; off >>= 1) {
                l0 += __shfl_down(l0, off, 16);
                l1 += __shfl_down(l1, off, 16);
            }
            int n2 = rowbase + quad * 4 + rr;
            if (l15 == 0 && n2 < N_NODES) {
                Out[(size_t)n2 * 2 + 0] = l0 + b0;
                Out[(size_t)n2 * 2 + 1] = l1 + b1;
            }
        }
    }
}

extern "C" void kernel_launch(void* const* d_in, const int* in_sizes, int n_in,
                              void* d_out, int out_size, void* d_ws, size_t ws_size,
                              hipStream_t stream)
{
    const float* x      = (const float*)d_in[0];
    const int*   ei     = (const int*)d_in[1];
    const int*   et     = (const int*)d_in[2];
    const float* Wrel1  = (const float*)d_in[3];
    const float* Wroot1 = (const float*)d_in[4];
    const float* b1     = (const float*)d_in[5];
    const float* Wrel2  = (const float*)d_in[6];
    const float* Wroot2 = (const float*)d_in[7];
    const float* b2     = (const float*)d_in[8];
    const float* Wc     = (const float*)d_in[9];
    const float* bc     = (const float*)d_in[10];
    float* out = (float*)d_out;

    char* ws = (char*)d_ws;
    size_t off = 0;
    auto alloc = [&](size_t bytes) {
        void* p = ws + off;
        off += (bytes + 255) & ~(size_t)255;
        return p;
    };
    unsigned short* xb    = (unsigned short*)alloc((size_t)PAD_N * IN_DIM * 2);
    unsigned short* h1b   = (unsigned short*)alloc((size_t)PAD_N * HID * 2);
    unsigned short* Wp    = (unsigned short*)alloc((size_t)2 * 12 * 8 * 64 * 8 * 2);
    unsigned*       rs    = (unsigned*)alloc((size_t)(M_SEG + 1) * 4);
    unsigned*       cursor= (unsigned*)alloc((size_t)M_SEG * 4);
    unsigned*       bsums = (unsigned*)alloc(256 * 4);
    unsigned*       csr   = (unsigned*)alloc((size_t)N_EDGES * 4);

    const int edge_blocks = (N_EDGES + 255) / 256;
    const int seg_blocks  = (M_SEG + 255) / 256;
    const int gemm_blocks = PAD_N / 64;                 // 1564
    const int prep_blocks = CVT_BLOCKS + PACK_BLOCKS + HIST_BLOCKS;

    // ---- CSR build + conversions (graph identical for both layers) ----
    hipMemsetAsync(cursor, 0, (size_t)M_SEG * 4, stream);
    prep_kernel<<<prep_blocks, 256, 0, stream>>>(
        x, xb, Wroot1, Wrel1, Wroot2, Wrel2, Wp, ei, et, cursor);
    scan1_kernel<<<SCAN_NB, 256, 0, stream>>>(cursor, rs, bsums);
    scan3_kernel<<<seg_blocks, 256, 0, stream>>>(rs, bsums, cursor);
    fill_kernel<<<edge_blocks, 256, 0, stream>>>(ei, et, cursor, csr);

    // ---- layer 1 (fused gather+gemm, LDS-staged B) ----
    gemm_kernel<false><<<gemm_blocks, 256, 0, stream>>>(
        xb, rs, csr, Wp, b1, h1b, nullptr, nullptr, nullptr);

    // ---- layer 2 (fused gather+gemm, FINAL classifier) ----
    gemm_kernel<true><<<gemm_blocks, 256, 0, stream>>>(
        h1b, rs, csr, Wp + (size_t)12 * 8 * 64 * 8, b2, nullptr, Wc, bc, out);
}

// Round 12
// 233.326 us; speedup vs baseline: 1.2639x; 1.0367x over previous
//
#include <hip/hip_runtime.h>
#include <hip/hip_fp16.h>

#define N_NODES 100000
#define PAD_N   100096                   // 782 * 128, padded M for GEMM tiles
#define IN_DIM 128
#define HID 128
#define N_REL 2
#define N_EDGES 500000
#define M_SEG (N_REL * N_NODES)          // 200000 (rel,node) segments
#define SCAN_BLK 1024
#define SCAN_NB ((M_SEG + SCAN_BLK - 1) / SCAN_BLK)   // 196

#define CVT_BLOCKS 12500                 // N_NODES*IN_DIM/4 / 256
#define PACK_BLOCKS 48                   // 2*12*8*64 / 256
#define HIST_BLOCKS 1954                 // ceil(N_EDGES/256)

#define GB_EDGES 48                      // gather window coverage (2 x 24-edge halves)

typedef __attribute__((ext_vector_type(8))) _Float16 half8;
typedef __attribute__((ext_vector_type(4))) float float4v;

__device__ __forceinline__ unsigned short f2h(float f) {
    return __half_as_ushort(__float2half(f));   // RNE
}

// ---------------------------------------------------------------------------
// Fused prep: cvt (x fp32->fp16) | pack (weights->B-frag order, fp16) | hist.
// Layer-1 pack uses PERMUTED channel order chan = l15*8 + nt so the gemm
// epilogue can write H with coalesced half8 stores while H memory stays in
// TRUE channel order (layer 2 needs no changes).  Layer-2 pack unchanged.
// ---------------------------------------------------------------------------
__global__ __launch_bounds__(256) void prep_kernel(
    const float* __restrict__ X, unsigned short* __restrict__ Xb,
    const float* __restrict__ Wroot1, const float* __restrict__ Wrel1,
    const float* __restrict__ Wroot2, const float* __restrict__ Wrel2,
    unsigned short* __restrict__ Wp,
    const int* __restrict__ ei, const int* __restrict__ et,
    unsigned* __restrict__ cnt)
{
    int bid = blockIdx.x;
    if (bid < CVT_BLOCKS) {
        int i = bid * 256 + threadIdx.x;
        if (i >= N_NODES * IN_DIM / 4) return;
        float4 v = ((const float4*)X)[i];
        ushort4 o;
        o.x = f2h(v.x); o.y = f2h(v.y); o.z = f2h(v.z); o.w = f2h(v.w);
        ((ushort4*)Xb)[i] = o;
    } else if (bid < CVT_BLOCKS + PACK_BLOCKS) {
        int tid = (bid - CVT_BLOCKS) * 256 + threadIdx.x;
        int layer = tid / 6144;
        int rem   = tid % 6144;
        int ks    = rem / 512;
        int rem2  = rem % 512;
        int nt    = rem2 / 64;
        int lane  = rem2 % 64;
        int seg = ks >> 2;
        int kl  = (ks & 3) * 32 + (lane >> 4) * 8;
        // layer 0: permuted N-channel order (coalesced H store); layer 1: MFMA order
        int chan = layer ? (nt * 16 + (lane & 15)) : ((lane & 15) * 8 + nt);
        const float* Wroot = layer ? Wroot2 : Wroot1;
        const float* Wrel  = layer ? Wrel2  : Wrel1;
        const float* W = (seg == 0) ? Wroot : (Wrel + (size_t)(seg - 1) * 128 * 128);
        unsigned short* dst = Wp + (size_t)tid * 8;
        #pragma unroll
        for (int j = 0; j < 8; ++j)
            dst[j] = f2h(W[(size_t)(kl + j) * 128 + chan]);
    } else {
        int e = (bid - CVT_BLOCKS - PACK_BLOCKS) * 256 + threadIdx.x;
        if (e >= N_EDGES) return;
        int dst = ei[N_EDGES + e];
        int r = et[e];
        atomicAdd(cnt + (size_t)r * N_NODES + dst, 1u);
    }
}

// ---------------------------------------------------------------------------
// Scan chain for CSR row starts (scan1 -> scan3; scan2 folded into scan3)
// ---------------------------------------------------------------------------
__global__ __launch_bounds__(256) void scan1_kernel(
    const unsigned* __restrict__ cnt,
    unsigned* __restrict__ rs, unsigned* __restrict__ bsums)
{
    __shared__ unsigned sdata[256];
    int t = threadIdx.x;
    int base = blockIdx.x * SCAN_BLK + t * 4;
    unsigned v[4]; unsigned s = 0;
    #pragma unroll
    for (int j = 0; j < 4; ++j) {
        v[j] = (base + j < M_SEG) ? cnt[base + j] : 0u;
        s += v[j];
    }
    sdata[t] = s;
    __syncthreads();
    #pragma unroll
    for (int off = 1; off < 256; off <<= 1) {
        unsigned x = (t >= off) ? sdata[t - off] : 0u;
        __syncthreads();
        if (t >= off) sdata[t] += x;
        __syncthreads();
    }
    unsigned excl = (t > 0) ? sdata[t - 1] : 0u;
    if (t == 255) bsums[blockIdx.x] = sdata[255];
    unsigned run = excl;
    #pragma unroll
    for (int j = 0; j < 4; ++j) {
        if (base + j < M_SEG) rs[base + j] = run;
        run += v[j];
    }
}

// scan3: each block redundantly scans the 196 block sums in LDS (trivial),
// then applies the offset.  Removes the serial single-block scan2 dispatch.
__global__ __launch_bounds__(256) void scan3_kernel(
    unsigned* __restrict__ rs, const unsigned* __restrict__ bsums,
    unsigned* __restrict__ cursor)
{
    __shared__ unsigned sdata[256];
    int t = threadIdx.x;
    sdata[t] = (t < SCAN_NB) ? bsums[t] : 0u;
    __syncthreads();
    #pragma unroll
    for (int off = 1; off < 256; off <<= 1) {
        unsigned x = (t >= off) ? sdata[t - off] : 0u;
        __syncthreads();
        if (t >= off) sdata[t] += x;
        __syncthreads();
    }
    int i = blockIdx.x * blockDim.x + t;
    if (i < M_SEG) {
        int b = i >> 10;
        unsigned add = (b > 0) ? sdata[b - 1] : 0u;
        unsigned v = rs[i] + add;
        rs[i] = v;
        cursor[i] = v;
    }
    if (i == 0) rs[M_SEG] = N_EDGES;
}

__global__ __launch_bounds__(256) void fill_kernel(
    const int* __restrict__ ei, const int* __restrict__ et,
    unsigned* __restrict__ cursor, unsigned* __restrict__ csr)
{
    int e = blockIdx.x * blockDim.x + threadIdx.x;
    if (e >= N_EDGES) return;
    int src = ei[e];
    int dst = ei[N_EDGES + e];
    int r = et[e];
    unsigned pos = atomicAdd(cursor + (size_t)r * N_NODES + dst, 1u);
    csr[pos] = (unsigned)src;
}

// ---------------------------------------------------------------------------
// Fused gather + MFMA GEMM (fp16), VMEM-issue-optimized v3:
//  * R11 base (LDS-staged B dbuf, coalesced H stores, shuffle-distributed
//    edge ids) PLUS counted-vmcnt gather pipelining (T3/T4 pattern):
//    - the wave's 12 KB buffer is split into two 6 KB halves (24 edges).
//      The typical window (<=48 edges/rel, >99%) is 4 fixed slots
//      (r0:0-24->A, r0:24-48->B, r1:0-24->A, r1:24-48->B).  Volleys are
//      UNCONDITIONAL 6-instruction bursts (clamped ids -> exact vmcnt
//      ledger).  Schedule: issue s0,s1 -> vmcnt(6) -> acc s0 -> lgkm(0) ->
//      issue s2 -> vmcnt(6) -> acc s1 -> issue s3 -> vmcnt(6) -> acc s2 ->
//      vmcnt(0) -> acc s3.  Every drain except the first overlaps an accum;
//      R11 exposed two full vmcnt(0) drains.
//    - per-node edge order preserved (batches monotonic within each rel).
//    - rare >48-edge windows: serial remainder loop (wave-uniform branch).
//  * 256 threads, default launch bounds (forced bounds spilled in r4/r5).
// ---------------------------------------------------------------------------
template <bool FINAL>
__global__ __launch_bounds__(256) void gemm_kernel(
    const unsigned short* __restrict__ Xin,   // [PAD_N][128] fp16 (layer input + gather source)
    const unsigned* __restrict__ rs,          // [M_SEG+1] CSR row starts
    const unsigned* __restrict__ csr,         // [N_EDGES] src node per slot
    const unsigned short* __restrict__ Wp,    // packed [12][8][64][8] fp16
    const float* __restrict__ bias,           // [128] fp32
    unsigned short* __restrict__ Hout,        // [PAD_N][128] fp16 (!FINAL)
    const float* __restrict__ Wc,             // [128][2] fp32 (FINAL)
    const float* __restrict__ bc,             // [2] fp32 (FINAL)
    float* __restrict__ Out)                  // [N][2] fp32 (FINAL)
{
    // 48 KB, time-shared: gather buffers (4 x 12 KB) then B dbuf (2 x 24 KB)
    __shared__ __align__(16) unsigned char lds_raw[49152];

    const int t    = threadIdx.x;
    const int w    = t >> 6;          // wave 0..3
    const int lane = t & 63;
    const int l15  = lane & 15;
    const int quad = lane >> 4;
    const int rowbase = blockIdx.x * 64 + w * 16;   // this wave's 16 nodes
    const int koff = quad * 8;
    unsigned char* myBuf = lds_raw + w * (GB_EDGES * 256);
    unsigned char* halfA = myBuf;
    unsigned char* halfB = myBuf + 24 * 256;
    unsigned short* ldsB = (unsigned short*)lds_raw;   // [2][3*8*512]

    const uint4* __restrict__ X4 = (const uint4*)Xin;   // 16B units

    // ---- seg-0 A-frags preloaded (latency hides under the gather) ----
    const unsigned short* aBase = Xin + (size_t)(rowbase + l15) * 128 + koff;
    half8 ax[4];
    #pragma unroll
    for (int ksl = 0; ksl < 4; ++ksl)
        ax[ksl] = *(const half8*)(aBase + ksl * 32);

    // ---- per-lane accumulators for the 2 relation means ----
    __half2 a2[2][4][4];              // [r][ksl][j] — statically indexed
    #pragma unroll
    for (int r = 0; r < 2; ++r)
        #pragma unroll
        for (int ksl = 0; ksl < 4; ++ksl)
            #pragma unroll
            for (int j = 0; j < 4; ++j)
                a2[r][ksl][j] = __float2half2_rn(0.f);

    const int node = rowbase + l15;
    float inv_[2] = {1.f, 1.f};

    // unconditional 6-instruction volley: 24 edge-rows into `half`.
    // ids via shuffle from idv (lane q of idv = edge S+q); indices clamped
    // to [0, cm) so the vmcnt ledger is exact even for short batches.
    auto volley6 = [&](unsigned idv, unsigned off, unsigned cm, unsigned char* half) {
        #pragma unroll
        for (int i = 0; i < 6; ++i) {
            unsigned eL = (unsigned)(i * 4) + (unsigned)(lane >> 4);   // 0..23
            unsigned srcIdx = off + eL;
            unsigned clampv = cm ? cm - 1u : 0u;
            srcIdx = srcIdx < cm ? srcIdx : clampv;
            unsigned id = (unsigned)__shfl((int)idv, (int)srcIdx, 64);
            unsigned cg = (unsigned)(lane & 15) ^ (eL & 7u);
            const unsigned short* gp =
                (const unsigned short*)(X4 + ((size_t)id << 4) + cg);
            __builtin_amdgcn_global_load_lds(
                (const __attribute__((address_space(1))) unsigned int*)gp,
                (__attribute__((address_space(3))) unsigned int*)(half + i * 1024),
                16, 0, 0);
        }
    };

    // accumulate this lane's node rows within batch [S+off, S+lim)
    auto accumB = [&](int r, unsigned S, unsigned off, unsigned lim,
                      unsigned st, unsigned en, const unsigned char* half) {
        unsigned gbase = S + off;
        unsigned lo = st > gbase ? st : gbase;
        unsigned hiB = S + lim;
        unsigned hi = en < hiB ? en : hiB;
        for (unsigned p = lo; p < hi; ++p) {
            unsigned eL = p - gbase;
            const unsigned char* rowb = half + eL * 256;
            #pragma unroll
            for (int ksl = 0; ksl < 4; ++ksl) {
                unsigned pos = ((unsigned)(ksl * 4 + quad)) ^ (eL & 7u);
                half8 h = *(const half8*)(rowb + pos * 16);
                #pragma unroll
                for (int j = 0; j < 4; ++j)
                    a2[r][ksl][j] = __hadd2(a2[r][ksl][j],
                                            ((const __half2*)&h)[j]);
            }
        }
    };

    if (rowbase < N_NODES) {          // 16-row windows are fully real or fully pad
        // bounds for both rels (wave-uniform S/E; per-lane st/en)
        unsigned S0 = rs[rowbase],               E0 = rs[rowbase + 16];
        unsigned st0 = rs[node],                 en0 = rs[node + 1];
        unsigned S1 = rs[N_NODES + rowbase],     E1 = rs[N_NODES + rowbase + 16];
        unsigned st1 = rs[N_NODES + node],       en1 = rs[N_NODES + node + 1];
        unsigned d0 = en0 - st0; inv_[0] = 1.0f / (float)(d0 ? d0 : 1u);
        unsigned d1 = en1 - st1; inv_[1] = 1.0f / (float)(d1 ? d1 : 1u);

        unsigned c0 = E0 - S0, c1 = E1 - S1;
        unsigned m0 = c0 > GB_EDGES ? GB_EDGES : c0;   // main-path coverage
        unsigned m1 = c1 > GB_EDGES ? GB_EDGES : c1;
        unsigned l0a = m0 > 24u ? 24u : m0;            // slot lims
        unsigned l1a = m1 > 24u ? 24u : m1;

        // id vectors for both rels (64 ids each, covers the 48-edge main path)
        unsigned q0 = S0 + (unsigned)lane;
        unsigned idv0 = c0 ? csr[q0 < E0 ? q0 : E0 - 1u] : 0u;
        unsigned q1 = S1 + (unsigned)lane;
        unsigned idv1 = c1 ? csr[q1 < E1 ? q1 : E1 - 1u] : 0u;

        // drain all prior VMEM so the counted-vmcnt ledger below is exact
        asm volatile("s_waitcnt vmcnt(0)" ::: "memory");
        __builtin_amdgcn_sched_barrier(0);

        // ---- 4-slot pipelined gather ----
        volley6(idv0, 0u,  m0, halfA);                 // s0
        volley6(idv0, 24u, m0, halfB);                 // s1
        asm volatile("s_waitcnt vmcnt(6)" ::: "memory");
        __builtin_amdgcn_sched_barrier(0);
        accumB(0, S0, 0u, l0a, st0, en0, halfA);       // acc s0 (s1,s2 in flight)
        asm volatile("s_waitcnt lgkmcnt(0)" ::: "memory");
        __builtin_amdgcn_sched_barrier(0);
        volley6(idv1, 0u, m1, halfA);                  // s2
        asm volatile("s_waitcnt vmcnt(6)" ::: "memory");
        __builtin_amdgcn_sched_barrier(0);
        accumB(0, S0, 24u, m0, st0, en0, halfB);       // acc s1
        asm volatile("s_waitcnt lgkmcnt(0)" ::: "memory");
        __builtin_amdgcn_sched_barrier(0);
        volley6(idv1, 24u, m1, halfB);                 // s3
        asm volatile("s_waitcnt vmcnt(6)" ::: "memory");
        __builtin_amdgcn_sched_barrier(0);
        accumB(1, S1, 0u, l1a, st1, en1, halfA);       // acc s2
        asm volatile("s_waitcnt vmcnt(0)" ::: "memory");
        __builtin_amdgcn_sched_barrier(0);
        accumB(1, S1, 24u, m1, st1, en1, halfB);       // acc s3

        // ---- remainder (>48 edges in a rel, <1% of windows; wave-uniform) ----
        #pragma unroll
        for (int r = 0; r < 2; ++r) {
            unsigned S  = r ? S1  : S0;
            unsigned E  = r ? E1  : E0;
            unsigned st = r ? st1 : st0;
            unsigned en = r ? en1 : en0;
            for (unsigned base = S + GB_EDGES; base < E; base += 24u) {
                unsigned cnt = E - base;
                if (cnt > 24u) cnt = 24u;
                unsigned q = base + (unsigned)lane;
                unsigned idv = csr[q < E ? q : E - 1u];
                asm volatile("s_waitcnt lgkmcnt(0)" ::: "memory");
                __builtin_amdgcn_sched_barrier(0);
                volley6(idv, 0u, cnt, halfA);
                asm volatile("s_waitcnt vmcnt(0)" ::: "memory");
                __builtin_amdgcn_sched_barrier(0);
                accumB(r, base, 0u, cnt, st, en, halfA);
            }
        }
    }

    // scale to means
    half8 ag[2][4];                   // [r][ksl]
    #pragma unroll
    for (int r = 0; r < 2; ++r) {
        __half2 s2 = __float2half2_rn(inv_[r]);
        #pragma unroll
        for (int ksl = 0; ksl < 4; ++ksl) {
            half8 h;
            #pragma unroll
            for (int j = 0; j < 4; ++j)
                ((__half2*)&h)[j] = __hmul2(a2[r][ksl][j], s2);
            ag[r][ksl] = h;
        }
    }

    __syncthreads();                  // all waves done with gather LDS

    // ---- MFMA phase: B double-buffered in LDS (R0 pattern, 6 stages/wave) ----
    auto stage = [&](int ph, int buf) {
        #pragma unroll
        for (int fi = 0; fi < 6; ++fi) {
            int f  = fi * 4 + w;          // 0..23
            int sl = f >> 3;              // phase-local K-step 0..2
            int nt = f & 7;
            int ks = ph * 3 + sl;
            const unsigned short* g = Wp + ((size_t)(ks * 8 + nt) * 64 + lane) * 8;
            unsigned short* l = ldsB + (size_t)buf * 12288 + (size_t)(sl * 8 + nt) * 512;
            __builtin_amdgcn_global_load_lds(
                (const __attribute__((address_space(1))) unsigned int*)g,
                (__attribute__((address_space(3))) unsigned int*)l, 16, 0, 0);
        }
    };

    float4v acc[8];
    #pragma unroll
    for (int nt = 0; nt < 8; ++nt) {
        float bv = FINAL ? bias[nt * 16 + l15] : bias[l15 * 8 + nt];
        acc[nt] = float4v{bv, bv, bv, bv};
    }

    stage(0, 0);
    __syncthreads();                  // phase-0 B staged (vmcnt drained)

    #pragma unroll
    for (int ph = 0; ph < 4; ++ph) {
        if (ph < 3) stage(ph + 1, (ph + 1) & 1);   // overlap staging with compute
        #pragma unroll
        for (int sl = 0; sl < 3; ++sl) {
            int ks = ph * 3 + sl;
            half8 b[8];
            #pragma unroll
            for (int nt = 0; nt < 8; ++nt)
                b[nt] = *(const half8*)(ldsB + (size_t)(ph & 1) * 12288 +
                                        (size_t)(sl * 8 + nt) * 512 + lane * 8);
            half8 A = (ks < 4) ? ax[ks] : ag[(ks >> 2) - 1][ks & 3];
            #pragma unroll
            for (int nt = 0; nt < 8; ++nt)
                acc[nt] = __builtin_amdgcn_mfma_f32_16x16x32_f16(A, b[nt], acc[nt], 0, 0, 0);
        }
        __syncthreads();   // readers done with buf(ph&1); stage(ph+1) drained
    }

    if (!FINAL) {
        // Permuted channels: lane's acc[0..7][rr] = channels l15*8 .. l15*8+7
        // of node rowbase + quad*4 + rr -> one coalesced half8 store per rr.
        #pragma unroll
        for (int rr = 0; rr < 4; ++rr) {
            int n2 = rowbase + quad * 4 + rr;
            __half2 hv[4];
            #pragma unroll
            for (int j = 0; j < 4; ++j)
                hv[j] = __floats2half2_rn(fmaxf(acc[2 * j][rr], 0.f),
                                          fmaxf(acc[2 * j + 1][rr], 0.f));
            *(uint4*)(Hout + (size_t)n2 * 128 + l15 * 8) = *(const uint4*)hv;
        }
    } else {
        float wc0[8], wc1[8];
        #pragma unroll
        for (int nt = 0; nt < 8; ++nt) {
            wc0[nt] = Wc[(nt * 16 + l15) * 2 + 0];
            wc1[nt] = Wc[(nt * 16 + l15) * 2 + 1];
        }
        float b0 = bc[0], b1 = bc[1];
        #pragma unroll
        for (int rr = 0; rr < 4; ++rr) {
            float l0 = 0.f, l1 = 0.f;
            #pragma unroll
            for (int nt = 0; nt < 8; ++nt) {
                float h = fmaxf(acc[nt][rr], 0.f);
                l0 += h * wc0[nt];
                l1 += h * wc1[nt];
            }
            #pragma unroll
            for (int off = 8; off > 0; off >>= 1) {
                l0 += __shfl_down(l0, off, 16);
                l1 += __shfl_down(l1, off, 16);
            }
            int n2 = rowbase + quad * 4 + rr;
            if (l15 == 0 && n2 < N_NODES) {
                Out[(size_t)n2 * 2 + 0] = l0 + b0;
                Out[(size_t)n2 * 2 + 1] = l1 + b1;
            }
        }
    }
}

extern "C" void kernel_launch(void* const* d_in, const int* in_sizes, int n_in,
                              void* d_out, int out_size, void* d_ws, size_t ws_size,
                              hipStream_t stream)
{
    const float* x      = (const float*)d_in[0];
    const int*   ei     = (const int*)d_in[1];
    const int*   et     = (const int*)d_in[2];
    const float* Wrel1  = (const float*)d_in[3];
    const float* Wroot1 = (const float*)d_in[4];
    const float* b1     = (const float*)d_in[5];
    const float* Wrel2  = (const float*)d_in[6];
    const float* Wroot2 = (const float*)d_in[7];
    const float* b2     = (const float*)d_in[8];
    const float* Wc     = (const float*)d_in[9];
    const float* bc     = (const float*)d_in[10];
    float* out = (float*)d_out;

    char* ws = (char*)d_ws;
    size_t off = 0;
    auto alloc = [&](size_t bytes) {
        void* p = ws + off;
        off += (bytes + 255) & ~(size_t)255;
        return p;
    };
    unsigned short* xb    = (unsigned short*)alloc((size_t)PAD_N * IN_DIM * 2);
    unsigned short* h1b   = (unsigned short*)alloc((size_t)PAD_N * HID * 2);
    unsigned short* Wp    = (unsigned short*)alloc((size_t)2 * 12 * 8 * 64 * 8 * 2);
    unsigned*       rs    = (unsigned*)alloc((size_t)(M_SEG + 1) * 4);
    unsigned*       cursor= (unsigned*)alloc((size_t)M_SEG * 4);
    unsigned*       bsums = (unsigned*)alloc(256 * 4);
    unsigned*       csr   = (unsigned*)alloc((size_t)N_EDGES * 4);

    const int edge_blocks = (N_EDGES + 255) / 256;
    const int seg_blocks  = (M_SEG + 255) / 256;
    const int gemm_blocks = PAD_N / 64;                 // 1564
    const int prep_blocks = CVT_BLOCKS + PACK_BLOCKS + HIST_BLOCKS;

    // ---- CSR build + conversions (graph identical for both layers) ----
    hipMemsetAsync(cursor, 0, (size_t)M_SEG * 4, stream);
    prep_kernel<<<prep_blocks, 256, 0, stream>>>(
        x, xb, Wroot1, Wrel1, Wroot2, Wrel2, Wp, ei, et, cursor);
    scan1_kernel<<<SCAN_NB, 256, 0, stream>>>(cursor, rs, bsums);
    scan3_kernel<<<seg_blocks, 256, 0, stream>>>(rs, bsums, cursor);
    fill_kernel<<<edge_blocks, 256, 0, stream>>>(ei, et, cursor, csr);

    // ---- layer 1 (fused gather+gemm, LDS-staged B) ----
    gemm_kernel<false><<<gemm_blocks, 256, 0, stream>>>(
        xb, rs, csr, Wp, b1, h1b, nullptr, nullptr, nullptr);

    // ---- layer 2 (fused gather+gemm, FINAL classifier) ----
    gemm_kernel<true><<<gemm_blocks, 256, 0, stream>>>(
        h1b, rs, csr, Wp + (size_t)12 * 8 * 64 * 8, b2, nullptr, Wc, bc, out);
}